// Round 4
// baseline (4613.149 us; speedup 1.0000x reference)
//
#include <hip/hip_runtime.h>
#include <hip/hip_bf16.h>
#include <hip/hip_cooperative_groups.h>

namespace cg = cooperative_groups;

// QLSTM: T=512, B=256, D=128, H=256.  z = [x,h] @ W^T + b, W=[4H,384]
// Round 12: r8/r11 core (proven best) + vmem scheduling discipline.
// Theory: vmcnt is per-wave and IN-ORDER, so r8's poll (s_waitcnt vmcnt(0))
// and loop-top x-stage drained the x HBM prefetch (~900cy) and the sc1
// slow-plane store ack (~600-900cy) into the chain critical path EVERY step.
// Changes (math identical, scheduling only):
//  - x prefetch issued AFTER poll success, 2 steps ahead; staged into comb_s
//    during the gates phase (x region dead after barrier2) -> its latency
//    hides under MFMA+gates, drained for free at the next poll.
//  - sc1 slow-plane mirror + hist stores moved to a dedicated SERVICE WAVE
//    (block = 320 = 4 compute waves + 1 service wave). Compute threads pass
//    tagged hwords through a 1KB LDS mailbox; service wave sc1-mirrors and
//    writes hist. Its vmcnt never gates the polling waves. Spin depends only
//    on own-block data -> no deadlock; fallback liveness preserved (slow
//    plane lags fast by ~1 phase).
//  - Poll-entry outstanding vmem = one plain h-store (~150cy exposed).
//  - 32KB LDS pad forces 1 block/CU (no persistent-block doubling).
//  - Keeps: r11 XCD-verified role claim, tagged dual-plane protocol, fused
//    asm poll, NPOLL fast tries + sc1 fallback.

#define T_STEPS 512
#define BATCH   256
#define DIN     128
#define HID     256
#define KDIM    384
#define LDK     392   // padded LDS row stride (shorts)
#define GRIDN   256
#define BLOCKT  320   // 4 compute waves + 1 service wave
#define NCOMP   256
#define NPOLL   96    // bounded fast-poll tries before sc1 fallback

typedef __attribute__((ext_vector_type(8))) short short8;
typedef __attribute__((ext_vector_type(4))) short short4v;
typedef __attribute__((ext_vector_type(4))) float f32x4;

// ---- bootstrap state (device globals; re-zeroed by init_k every launch) ----
__device__ unsigned boot_percxd[8];
__device__ unsigned boot_claimed[8];   // 256-bit role bitmask

__device__ __forceinline__ unsigned short f2bf(float f) {
    unsigned u = __float_as_uint(f);
    unsigned r = (u + 0x7FFFu + ((u >> 16) & 1u)) >> 16;
    return (unsigned short)r;
}
__device__ __forceinline__ float bf2f(unsigned short s) {
    return __uint_as_float(((unsigned)s) << 16);
}
__device__ __forceinline__ float sigmoid_f(float x) {
    return 1.f / (1.f + __expf(-x));
}
__device__ __forceinline__ float tanh_f(float x) {
    float e = __expf(2.f * x);
    return 1.f - 2.f / (e + 1.f);
}
// ---- fused poll loads: 4 x dwordx4 + waitcnt in ONE asm block (r4 idiom) ----
__device__ __forceinline__ void poll_load_sc0(const unsigned int* p, uint4& a,
                                              uint4& b, uint4& c, uint4& d) {
    asm volatile(
        "global_load_dwordx4 %0, %4, off sc0\n\t"
        "global_load_dwordx4 %1, %4, off offset:16 sc0\n\t"
        "global_load_dwordx4 %2, %4, off offset:32 sc0\n\t"
        "global_load_dwordx4 %3, %4, off offset:48 sc0\n\t"
        "s_waitcnt vmcnt(0)"
        : "=&v"(a), "=&v"(b), "=&v"(c), "=&v"(d) : "v"(p) : "memory");
}
__device__ __forceinline__ void poll_load_sc1(const unsigned int* p, uint4& a,
                                              uint4& b, uint4& c, uint4& d) {
    asm volatile(
        "global_load_dwordx4 %0, %4, off sc1\n\t"
        "global_load_dwordx4 %1, %4, off offset:16 sc1\n\t"
        "global_load_dwordx4 %2, %4, off offset:32 sc1\n\t"
        "global_load_dwordx4 %3, %4, off offset:48 sc1\n\t"
        "s_waitcnt vmcnt(0)"
        : "=&v"(a), "=&v"(b), "=&v"(c), "=&v"(d) : "v"(p) : "memory");
}
__device__ __forceinline__ void store_plain_u32(unsigned int* p, unsigned int v) {
    asm volatile("global_store_dword %0, %1, off" :: "v"(p), "v"(v) : "memory");
}
__device__ __forceinline__ void store_sc1_u32(unsigned int* p, unsigned int v) {
    asm volatile("global_store_dword %0, %1, off sc1" :: "v"(p), "v"(v) : "memory");
}
__device__ __forceinline__ unsigned pack2bf(unsigned lo, unsigned hi) {
    return (hi & 0xFFFF0000u) | (lo >> 16);
}
__device__ __forceinline__ bool tags_ok(const uint4& a, const uint4& b,
                                        const uint4& c, const uint4& d,
                                        unsigned tag) {
    return ((a.x ^ tag) & 0xFFFFu) == 0 && ((a.y ^ tag) & 0xFFFFu) == 0 &&
           ((a.z ^ tag) & 0xFFFFu) == 0 && ((a.w ^ tag) & 0xFFFFu) == 0 &&
           ((b.x ^ tag) & 0xFFFFu) == 0 && ((b.y ^ tag) & 0xFFFFu) == 0 &&
           ((b.z ^ tag) & 0xFFFFu) == 0 && ((b.w ^ tag) & 0xFFFFu) == 0 &&
           ((c.x ^ tag) & 0xFFFFu) == 0 && ((c.y ^ tag) & 0xFFFFu) == 0 &&
           ((c.z ^ tag) & 0xFFFFu) == 0 && ((c.w ^ tag) & 0xFFFFu) == 0 &&
           ((d.x ^ tag) & 0xFFFFu) == 0 && ((d.y ^ tag) & 0xFFFFu) == 0 &&
           ((d.z ^ tag) & 0xFFFFu) == 0 && ((d.w ^ tag) & 0xFFFFu) == 0;
}

// ---- pack weights: Wpack[n][k] bf16, n = g*256 + j, row-major [1024][384] ----
__global__ __launch_bounds__(256) void pack_w(
    const float* __restrict__ Wf, const float* __restrict__ Wi,
    const float* __restrict__ Wg, const float* __restrict__ Wo,
    unsigned short* __restrict__ Wp) {
    int idx = blockIdx.x * 256 + threadIdx.x;
    int n = idx / KDIM;
    int k = idx - n * KDIM;
    int g = n >> 8, j = n & 255;
    const float* s = (g == 0) ? Wf : (g == 1) ? Wi : (g == 2) ? Wg : Wo;
    Wp[idx] = f2bf(s[j * KDIM + k]);
}

__global__ __launch_bounds__(256) void pack_b(
    const float* __restrict__ bf, const float* __restrict__ bi,
    const float* __restrict__ bg, const float* __restrict__ bo,
    float* __restrict__ bp) {
    int n = blockIdx.x * 256 + threadIdx.x;
    int g = n >> 8, j = n & 255;
    const float* s = (g == 0) ? bf : (g == 1) ? bi : (g == 2) ? bg : bo;
    bp[n] = s[j];
}

// ---- zero exchange planes + bootstrap state (h_0 = 0, tag 0) ----
__global__ __launch_bounds__(256) void init_k(unsigned int* __restrict__ hxp) {
    int tid = blockIdx.x * 256 + threadIdx.x;   // grid 256 -> 65536
    hxp[tid] = 0u;
    hxp[65536 + tid] = 0u;
    hxp[131072 + tid] = 0u;
    hxp[196608 + tid] = 0u;
    if (tid < 8) {
        boot_percxd[tid] = 0u;
        boot_claimed[tid] = 0u;
    }
}

// ---- persistent LSTM: all 512 steps in one launch ----
__global__ __launch_bounds__(BLOCKT, 1) void lstm_persist(
    const float* __restrict__ X,            // [T,B,D] fp32
    const unsigned short* __restrict__ W,   // [1024][384] bf16
    const float* __restrict__ bias,         // [1024]
    unsigned int* __restrict__ hxp,         // fast[2][B][H] + slow[2][B][H]
    unsigned short* __restrict__ hist,      // [T][B][H] bf16
    float* __restrict__ out) {
    __shared__ __align__(16) unsigned short W_s[64 * LDK];    // 50176 B
    __shared__ __align__(16) unsigned short comb_s[16 * LDK]; // 12544 B
    __shared__ __align__(16) float z_s[4 * 272];              // 4352 B
    __shared__ __align__(16) unsigned hw_lds[NCOMP];          // 1024 B mailbox
    __shared__ char pad_s[32768];   // occupancy pad: force 1 block/CU
    __shared__ int fastok_s;
    __shared__ int role_s;

    const int tid = threadIdx.x;    // 0..319

    // ---- XCD-verified role claim (r11, proven-neutral, keeps placement) ----
    if (tid == 0) {
        unsigned xcc = __builtin_amdgcn_s_getreg((31u << 11) | 20u) & 7u;
        unsigned slot = atomicAdd(&boot_percxd[xcc], 1u);
        int role = -1;
        if (slot < 32u) {
            role = (int)(xcc * 32u + slot);
            atomicOr(&boot_claimed[role >> 5], 1u << (role & 31));
        }
        role_s = role;
        fastok_s = 1;
    }
    __syncthreads();
    cg::this_grid().sync();      // all claims visible before spill scan
    if (role_s < 0) {            // overflow block: grab any unclaimed role
        if (tid == 0) {
            for (int r = 0; r < 256; ++r) {
                unsigned bit = 1u << (r & 31);
                if (!(atomicOr(&boot_claimed[r >> 5], bit) & bit)) {
                    role_s = r;
                    break;
                }
            }
        }
        __syncthreads();
    }
    const int role = role_s;
    if (role == -12345) pad_s[0] = 1;   // keep occupancy pad allocated

    const int bg = role >> 4, jg = role & 15;   // chain bg: 16 same-XCD blocks
    const int b0 = bg * 16, j0 = jg * 16;
    const int wave = tid >> 6, lane = tid & 63;
    const int l16 = lane & 15, quad = lane >> 4;
    const int bi = tid >> 4, jj = tid & 15;
    const int b = b0 + bi, j = j0 + jj;

    // stage W tile once (compute threads only): 64x384
    if (tid < NCOMP) {
#pragma unroll
        for (int c = 0; c < 12; ++c) {
            int q = c * 256 + tid;
            int row = q / 48, c8 = q - row * 48;
            int g = row >> 4, jr = row & 15;
            short8 v = *(const short8*)(W + ((g * 256 + j0 + jr) * KDIM + c8 * 8));
            *(short8*)(&W_s[row * LDK + c8 * 8]) = v;
        }
        hw_lds[tid] = 0u;
    }
    float bs0 = 0.f, bs1 = 0.f, bs2 = 0.f, bs3 = 0.f;
    if (tid < NCOMP) {
        bs0 = bias[0 * HID + j];
        bs1 = bias[1 * HID + j];
        bs2 = bias[2 * HID + j];
        bs3 = bias[3 * HID + j];
    }

    float c_reg = 0.f;
    float h_final = 0.f;

    const unsigned short* arow = &comb_s[l16 * LDK + quad * 8];
    const unsigned short* brow = &W_s[(wave * 16 + l16) * LDK + quad * 8];
    const int hrow = tid >> 4, hc = tid & 15;
    const int xr0 = tid >> 5, xc4 = tid & 31, xr1 = (tid + 256) >> 5;

    // service-wave constants (tid >= 256)
    const int sv = tid - NCOMP;          // 0..63
    const int t4 = sv * 4;
    const int bs_b = b0 + (t4 >> 4), bs_j = j0 + (t4 & 15);

    // ---- x prologue (compute only): stage x_0 now; x_1 -> set B ----
    float4 xA0, xA1, xB0, xB1;
    if (tid < NCOMP) {
        const float* x0b = X + b0 * DIN;
        float4 t0 = *(const float4*)(x0b + xr0 * DIN + xc4 * 4);
        float4 t1 = *(const float4*)(x0b + xr1 * DIN + xc4 * 4);
        short4v r;
        r.x = (short)f2bf(t0.x); r.y = (short)f2bf(t0.y);
        r.z = (short)f2bf(t0.z); r.w = (short)f2bf(t0.w);
        *(short4v*)(&comb_s[xr0 * LDK + xc4 * 4]) = r;
        r.x = (short)f2bf(t1.x); r.y = (short)f2bf(t1.y);
        r.z = (short)f2bf(t1.z); r.w = (short)f2bf(t1.w);
        *(short4v*)(&comb_s[xr1 * LDK + xc4 * 4]) = r;
        const float* x1b = X + (size_t)1 * BATCH * DIN + b0 * DIN;
        xB0 = *(const float4*)(x1b + xr0 * DIN + xc4 * 4);
        xB1 = *(const float4*)(x1b + xr1 * DIN + xc4 * 4);
    }
    __syncthreads();

    for (int k = 0; k < T_STEPS; ++k) {
        // ======== phase A: poll (compute) | sc1-mirror + hist (service) =====
        if (tid < NCOMP) {
            const unsigned tag = (unsigned)k;
            const unsigned int* fb =
                hxp + (k & 1) * 65536 + (b0 + hrow) * HID + hc * 16;
            const unsigned int* sb = fb + 131072;    // slow plane
            uint4 a, bq, cq, d;
            const int usefast = fastok_s;            // racy read ok (hint)

            if (usefast) {
                int tries = NPOLL;
                bool ok = false;
                for (;;) {
                    poll_load_sc0(fb, a, bq, cq, d);
                    if (tags_ok(a, bq, cq, d, tag)) { ok = true; break; }
                    if (--tries == 0) break;
                }
                if (!ok) {                   // bounded fallback: ALWAYS succeeds
                    fastok_s = 0;
                    for (;;) {
                        poll_load_sc1(sb, a, bq, cq, d);
                        if (tags_ok(a, bq, cq, d, tag)) break;
                        __builtin_amdgcn_s_sleep(1);
                    }
                }
            } else {
                for (;;) {
                    poll_load_sc1(sb, a, bq, cq, d);
                    if (tags_ok(a, bq, cq, d, tag)) break;
                    __builtin_amdgcn_s_sleep(1);
                }
            }

            // x prefetch for step k+2 (post-poll: never drained by the poll;
            // lands during MFMA+gates). set[k&1]: even k -> A, odd -> B.
            if (k + 2 < T_STEPS) {
                const float* xn = X + (size_t)(k + 2) * BATCH * DIN + b0 * DIN;
                if (k & 1) {
                    xB0 = *(const float4*)(xn + xr0 * DIN + xc4 * 4);
                    xB1 = *(const float4*)(xn + xr1 * DIN + xc4 * 4);
                } else {
                    xA0 = *(const float4*)(xn + xr0 * DIN + xc4 * 4);
                    xA1 = *(const float4*)(xn + xr1 * DIN + xc4 * 4);
                }
            }
            __builtin_amdgcn_sched_barrier(0);   // pin prefetch issue here

            // extract 16 bf16 -> comb_s[hrow][DIN + hc*16 ..]
            uint4 p0, p1;
            p0.x = pack2bf(a.x, a.y);   p0.y = pack2bf(a.z, a.w);
            p0.z = pack2bf(bq.x, bq.y); p0.w = pack2bf(bq.z, bq.w);
            p1.x = pack2bf(cq.x, cq.y); p1.y = pack2bf(cq.z, cq.w);
            p1.z = pack2bf(d.x, d.y);   p1.w = pack2bf(d.z, d.w);
            *(uint4*)(&comb_s[hrow * LDK + DIN + hc * 16]) = p0;
            *(uint4*)(&comb_s[hrow * LDK + DIN + hc * 16 + 8]) = p1;
        } else if (k > 0) {
            // service: mirror hwords tag=k (written at gates of step k-1)
            volatile unsigned* hw = hw_lds;
            unsigned w0, w1, w2, w3;
            const unsigned tag = (unsigned)k;
            for (;;) {
                w0 = hw[t4]; w1 = hw[t4 + 1]; w2 = hw[t4 + 2]; w3 = hw[t4 + 3];
                if (((w0 ^ tag) & 0xFFFFu) == 0 && ((w1 ^ tag) & 0xFFFFu) == 0 &&
                    ((w2 ^ tag) & 0xFFFFu) == 0 && ((w3 ^ tag) & 0xFFFFu) == 0)
                    break;
            }
            unsigned int* sd =
                hxp + 131072 + (k & 1) * 65536 + bs_b * HID + bs_j;
            store_sc1_u32(sd + 0, w0);
            store_sc1_u32(sd + 1, w1);
            store_sc1_u32(sd + 2, w2);
            store_sc1_u32(sd + 3, w3);
            uint2 hp;
            hp.x = pack2bf(w0, w1);
            hp.y = pack2bf(w2, w3);
            *(uint2*)(&hist[(size_t)(k - 1) * BATCH * HID +
                            (size_t)bs_b * HID + bs_j]) = hp;
            asm volatile("s_waitcnt vmcnt(16)" ::: "memory");  // cap outstanding
        }
        __syncthreads();   // barrier 1: h staged

        // ======== phase B: MFMA (compute) ========
        if (tid < NCOMP) {
            f32x4 acc0 = {0.f, 0.f, 0.f, 0.f}, acc1 = {0.f, 0.f, 0.f, 0.f};
#pragma unroll
            for (int kt = 0; kt < 6; ++kt) {
                short8 a0 = *(const short8*)(arow + (2 * kt) * 32);
                short8 b0v = *(const short8*)(brow + (2 * kt) * 32);
                short8 a1 = *(const short8*)(arow + (2 * kt + 1) * 32);
                short8 b1v = *(const short8*)(brow + (2 * kt + 1) * 32);
                acc0 = __builtin_amdgcn_mfma_f32_16x16x32_bf16(a0, b0v, acc0, 0, 0, 0);
                acc1 = __builtin_amdgcn_mfma_f32_16x16x32_bf16(a1, b1v, acc1, 0, 0, 0);
            }
#pragma unroll
            for (int r = 0; r < 4; ++r)
                z_s[wave * 272 + (quad * 4 + r) * 17 + l16] = acc0[r] + acc1[r];
        }
        __syncthreads();   // barrier 2: z staged; comb x-region now dead

        // ======== phase C: stage x_{k+1}; gates; plain store; mailbox =======
        if (tid < NCOMP) {
            if (k + 1 < T_STEPS) {
                // set[(k+1)&1] was loaded at step k-1 -> fully landed
                float4 s0 = ((k + 1) & 1) ? xB0 : xA0;
                float4 s1 = ((k + 1) & 1) ? xB1 : xA1;
                short4v r;
                r.x = (short)f2bf(s0.x); r.y = (short)f2bf(s0.y);
                r.z = (short)f2bf(s0.z); r.w = (short)f2bf(s0.w);
                *(short4v*)(&comb_s[xr0 * LDK + xc4 * 4]) = r;
                r.x = (short)f2bf(s1.x); r.y = (short)f2bf(s1.y);
                r.z = (short)f2bf(s1.z); r.w = (short)f2bf(s1.w);
                *(short4v*)(&comb_s[xr1 * LDK + xc4 * 4]) = r;
            }
            float zf = z_s[0 * 272 + bi * 17 + jj] + bs0;
            float zi = z_s[1 * 272 + bi * 17 + jj] + bs1;
            float zg = z_s[2 * 272 + bi * 17 + jj] + bs2;
            float zo = z_s[3 * 272 + bi * 17 + jj] + bs3;
            float fg = sigmoid_f(zf);
            float ig = sigmoid_f(zi);
            float gg = tanh_f(zg);
            float og = sigmoid_f(zo);
            c_reg = fg * c_reg + ig * gg;
            float hval = og * tanh_f(c_reg);
            unsigned short hb = f2bf(hval);
            unsigned int hword = ((unsigned)hb << 16) | (unsigned)(k + 1);
            unsigned int* fdst = hxp + ((k + 1) & 1) * 65536 + b * HID + j;
            store_plain_u32(fdst, hword);           // fast plane (same-XCD L2)
            ((volatile unsigned*)hw_lds)[tid] = hword;   // mailbox for service
            if (k + 1 == T_STEPS) h_final = hval;
        }
    }

    if (tid >= NCOMP) {
        // final mirror: tag 512 -> hist[511] (+ harmless slow-plane write)
        volatile unsigned* hw = hw_lds;
        unsigned w0, w1, w2, w3;
        const unsigned tag = (unsigned)T_STEPS;
        for (;;) {
            w0 = hw[t4]; w1 = hw[t4 + 1]; w2 = hw[t4 + 2]; w3 = hw[t4 + 3];
            if (((w0 ^ tag) & 0xFFFFu) == 0 && ((w1 ^ tag) & 0xFFFFu) == 0 &&
                ((w2 ^ tag) & 0xFFFFu) == 0 && ((w3 ^ tag) & 0xFFFFu) == 0)
                break;
        }
        unsigned int* sd =
            hxp + 131072 + (T_STEPS & 1) * 65536 + bs_b * HID + bs_j;
        store_sc1_u32(sd + 0, w0);
        store_sc1_u32(sd + 1, w1);
        store_sc1_u32(sd + 2, w2);
        store_sc1_u32(sd + 3, w3);
        uint2 hp;
        hp.x = pack2bf(w0, w1);
        hp.y = pack2bf(w2, w3);
        *(uint2*)(&hist[(size_t)(T_STEPS - 1) * BATCH * HID +
                        (size_t)bs_b * HID + bs_j]) = hp;
    } else {
        // epilogue: hx (fp32) and cx outputs
        out[T_STEPS * BATCH * 2 + b * HID + j] = h_final;
        out[T_STEPS * BATCH * 2 + BATCH * HID + b * HID + j] = c_reg;
    }
}

// ---- classifier head: one wave per (t,b) row ----
__global__ __launch_bounds__(256) void probs_k(
    const unsigned short* __restrict__ hist, const float* __restrict__ Wc,
    const float* __restrict__ bc, float* __restrict__ out) {
    const int wave = threadIdx.x >> 6, lane = threadIdx.x & 63;
    const size_t row = (size_t)blockIdx.x * 4 + wave;   // row = t*256+b < 131072
    const unsigned short* h = hist + row * HID;
    short4v hv = *(const short4v*)(h + lane * 4);
    const float4 wv = *(const float4*)(Wc + lane * 4);
    float p = bf2f((unsigned short)hv.x) * wv.x + bf2f((unsigned short)hv.y) * wv.y +
              bf2f((unsigned short)hv.z) * wv.z + bf2f((unsigned short)hv.w) * wv.w;
#pragma unroll
    for (int off = 32; off >= 1; off >>= 1) p += __shfl_down(p, off);
    if (lane == 0) {
        float prob = 1.f / (1.f + __expf(-(p + bc[0])));
        out[row * 2]     = prob;
        out[row * 2 + 1] = 1.f - prob;
    }
}

extern "C" void kernel_launch(void* const* d_in, const int* in_sizes, int n_in,
                              void* d_out, int out_size, void* d_ws, size_t ws_size,
                              hipStream_t stream) {
    const float* X  = (const float*)d_in[0];
    const float* Wf = (const float*)d_in[1];
    const float* bfp= (const float*)d_in[2];
    const float* Wi = (const float*)d_in[3];
    const float* bip= (const float*)d_in[4];
    const float* Wg = (const float*)d_in[5];
    const float* bgp= (const float*)d_in[6];
    const float* Wo = (const float*)d_in[7];
    const float* bop= (const float*)d_in[8];
    const float* Wc = (const float*)d_in[9];
    const float* bc = (const float*)d_in[10];
    float* out = (float*)d_out;

    char* ws = (char*)d_ws;
    unsigned short* Wpack = (unsigned short*)(ws);               // 786432 B
    float* bias = (float*)(ws + 786432);                         // 4096 B
    unsigned int* hxp = (unsigned int*)(ws + 790528);            // 1048576 B
    unsigned short* hist = (unsigned short*)(ws + 1839104);      // 67108864 B

    pack_w<<<1536, 256, 0, stream>>>(Wf, Wi, Wg, Wo, Wpack);
    pack_b<<<4, 256, 0, stream>>>(bfp, bip, bgp, bop, bias);
    init_k<<<256, 256, 0, stream>>>(hxp);

    void* kargs[6] = {(void*)&X, (void*)&Wpack, (void*)&bias,
                      (void*)&hxp, (void*)&hist, (void*)&out};
    (void)hipLaunchCooperativeKernel((const void*)lstm_persist, dim3(GRIDN),
                                     dim3(BLOCKT), kargs, 0, stream);

    probs_k<<<32768, 256, 0, stream>>>(hist, Wc, bc, out);
}

// Round 5
// 3091.327 us; speedup vs baseline: 1.4923x; 1.4923x over previous
//
#include <hip/hip_runtime.h>
#include <hip/hip_bf16.h>

// QLSTM: T=512, B=256, D=128, H=256.  z = [x,h] @ W^T + b, W=[4H,384]
// Round 13: r8's proven exchange protocol + gate-interleaved W packing.
//  - Wpack rows n = j*4 + g (gates interleaved). Wave w's 16 MFMA output
//    cols = 4 j-values x 4 gates -> after MFMA, a 4x4 lane<->reg butterfly
//    transpose (4 shfl_xor within 4-lane groups) gives each thread its
//    (b,j) with ALL FOUR gate pre-activations in register. z never touches
//    LDS; barrier 2 and z_s are gone. ONE barrier per step.
//  - W slice lives in VGPRs (12 x short8 = 48 regs/lane): no W_s, no W
//    ds_reads -> kills the dominant LDS bank conflicts (6.7e7 counted in r8,
//    ~512 cycles/step/block).
//  - comb_s double-buffered by step parity (2 x 16 x LDK): h_k and x_k both
//    staged in phase P of step k into buf[k&1]; safe because buf[p]'s prior
//    reader (MFMA of step k-2) finished before barrier k-1.
//  - x prefetch issued immediately AFTER the barrier (start of MFMA phase) --
//    the r12 lesson: __syncthreads drains vmcnt(0), so a prefetch issued
//    before a barrier is drained INTO the critical path. Here it has
//    MFMA+transpose+gates+poll (~700cy) to land, drained free at next poll.
//  - Poll protocol, tagged dual-plane stores, NPOLL fast tries + sc1
//    fallback, chain = blockIdx&15: r8 verbatim (r11 proved placement ok).

#define T_STEPS 512
#define BATCH   256
#define DIN     128
#define HID     256
#define KDIM    384
#define LDK     392   // padded LDS row stride (shorts)
#define GRIDN   256
#define NPOLL   96    // bounded fast-poll tries before sc1 fallback

typedef __attribute__((ext_vector_type(8))) short short8;
typedef __attribute__((ext_vector_type(4))) short short4v;
typedef __attribute__((ext_vector_type(4))) float f32x4;

__device__ __forceinline__ unsigned short f2bf(float f) {
    unsigned u = __float_as_uint(f);
    unsigned r = (u + 0x7FFFu + ((u >> 16) & 1u)) >> 16;
    return (unsigned short)r;
}
__device__ __forceinline__ float bf2f(unsigned short s) {
    return __uint_as_float(((unsigned)s) << 16);
}
__device__ __forceinline__ float sigmoid_f(float x) {
    return 1.f / (1.f + __expf(-x));
}
__device__ __forceinline__ float tanh_f(float x) {
    float e = __expf(2.f * x);
    return 1.f - 2.f / (e + 1.f);
}
// ---- fused poll loads: 4 x dwordx4 + waitcnt in ONE asm block (r4 idiom) ----
__device__ __forceinline__ void poll_load_sc0(const unsigned int* p, uint4& a,
                                              uint4& b, uint4& c, uint4& d) {
    asm volatile(
        "global_load_dwordx4 %0, %4, off sc0\n\t"
        "global_load_dwordx4 %1, %4, off offset:16 sc0\n\t"
        "global_load_dwordx4 %2, %4, off offset:32 sc0\n\t"
        "global_load_dwordx4 %3, %4, off offset:48 sc0\n\t"
        "s_waitcnt vmcnt(0)"
        : "=&v"(a), "=&v"(b), "=&v"(c), "=&v"(d) : "v"(p) : "memory");
}
__device__ __forceinline__ void poll_load_sc1(const unsigned int* p, uint4& a,
                                              uint4& b, uint4& c, uint4& d) {
    asm volatile(
        "global_load_dwordx4 %0, %4, off sc1\n\t"
        "global_load_dwordx4 %1, %4, off offset:16 sc1\n\t"
        "global_load_dwordx4 %2, %4, off offset:32 sc1\n\t"
        "global_load_dwordx4 %3, %4, off offset:48 sc1\n\t"
        "s_waitcnt vmcnt(0)"
        : "=&v"(a), "=&v"(b), "=&v"(c), "=&v"(d) : "v"(p) : "memory");
}
__device__ __forceinline__ void store_plain_u32(unsigned int* p, unsigned int v) {
    asm volatile("global_store_dword %0, %1, off" :: "v"(p), "v"(v) : "memory");
}
__device__ __forceinline__ void store_sc1_u32(unsigned int* p, unsigned int v) {
    asm volatile("global_store_dword %0, %1, off sc1" :: "v"(p), "v"(v) : "memory");
}
__device__ __forceinline__ unsigned pack2bf(unsigned lo, unsigned hi) {
    return (hi & 0xFFFF0000u) | (lo >> 16);
}
__device__ __forceinline__ bool tags_ok(const uint4& a, const uint4& b,
                                        const uint4& c, const uint4& d,
                                        unsigned tag) {
    return ((a.x ^ tag) & 0xFFFFu) == 0 && ((a.y ^ tag) & 0xFFFFu) == 0 &&
           ((a.z ^ tag) & 0xFFFFu) == 0 && ((a.w ^ tag) & 0xFFFFu) == 0 &&
           ((b.x ^ tag) & 0xFFFFu) == 0 && ((b.y ^ tag) & 0xFFFFu) == 0 &&
           ((b.z ^ tag) & 0xFFFFu) == 0 && ((b.w ^ tag) & 0xFFFFu) == 0 &&
           ((c.x ^ tag) & 0xFFFFu) == 0 && ((c.y ^ tag) & 0xFFFFu) == 0 &&
           ((c.z ^ tag) & 0xFFFFu) == 0 && ((c.w ^ tag) & 0xFFFFu) == 0 &&
           ((d.x ^ tag) & 0xFFFFu) == 0 && ((d.y ^ tag) & 0xFFFFu) == 0 &&
           ((d.z ^ tag) & 0xFFFFu) == 0 && ((d.w ^ tag) & 0xFFFFu) == 0;
}

// ---- pack weights: Wpack[n][k] bf16, n = j*4 + g (GATE-INTERLEAVED) ----
__global__ __launch_bounds__(256) void pack_w(
    const float* __restrict__ Wf, const float* __restrict__ Wi,
    const float* __restrict__ Wg, const float* __restrict__ Wo,
    unsigned short* __restrict__ Wp) {
    int idx = blockIdx.x * 256 + threadIdx.x;
    int n = idx / KDIM;
    int k = idx - n * KDIM;
    int j = n >> 2, g = n & 3;
    const float* s = (g == 0) ? Wf : (g == 1) ? Wi : (g == 2) ? Wg : Wo;
    Wp[idx] = f2bf(s[j * KDIM + k]);
}

// ---- pack bias: bp[n], n = j*4 + g (4 gates of one j contiguous) ----
__global__ __launch_bounds__(256) void pack_b(
    const float* __restrict__ bf, const float* __restrict__ bi,
    const float* __restrict__ bg, const float* __restrict__ bo,
    float* __restrict__ bp) {
    int n = blockIdx.x * 256 + threadIdx.x;
    int j = n >> 2, g = n & 3;
    const float* s = (g == 0) ? bf : (g == 1) ? bi : (g == 2) ? bg : bo;
    bp[n] = s[j];
}

// ---- zero all 4 exchange planes: fast[2] + slow[2] (h_0 = 0, tag 0) ----
__global__ __launch_bounds__(256) void init_k(unsigned int* __restrict__ hxp) {
    int tid = blockIdx.x * 256 + threadIdx.x;   // grid 256 -> 65536
    hxp[tid] = 0u;
    hxp[65536 + tid] = 0u;
    hxp[131072 + tid] = 0u;
    hxp[196608 + tid] = 0u;
}

// ---- persistent LSTM: all 512 steps in one launch ----
__global__ __launch_bounds__(256, 1) void lstm_persist(
    const float* __restrict__ X,            // [T,B,D] fp32
    const unsigned short* __restrict__ W,   // [1024][384] bf16, n=j*4+g
    const float* __restrict__ bias,         // [1024], n=j*4+g
    unsigned int* __restrict__ hxp,         // fast[2][B][H] + slow[2][B][H]
    unsigned short* __restrict__ hist,      // [T][B][H] bf16
    float* __restrict__ out) {
    __shared__ __align__(16) unsigned short comb_s[2 * 16 * LDK]; // 25088 B
    __shared__ int fastok_s;

    const int tid = threadIdx.x;
    const int bg = blockIdx.x & 15, jg = blockIdx.x >> 4;   // r8 chain mapping
    const int b0 = bg * 16, j0 = jg * 16;
    const int wave = tid >> 6, lane = tid & 63;
    const int l16 = lane & 15, quad = lane >> 4;
    const int hrow = tid >> 4, hc = tid & 15;
    const int xr0 = tid >> 5, xc4 = tid & 31, xr1 = (tid + 256) >> 5;

    // this thread's (b,j) after the butterfly transpose:
    const int b = b0 + quad * 4 + (l16 & 3);
    const int j = j0 + (wave << 2) + (l16 >> 2);

    // ---- W slice into registers: wave w -> rows n = 4*(j0+4w) + l16 ----
    const unsigned short* wrow =
        W + (size_t)(4 * (j0 + (wave << 2)) + l16) * KDIM + quad * 8;
    short8 wb[12];
#pragma unroll
    for (int kt = 0; kt < 12; ++kt) wb[kt] = *(const short8*)(wrow + kt * 32);

    const float4 bb = *(const float4*)(bias + j * 4);   // f,i,g,o for this j
    if (tid == 0) fastok_s = 1;

    float c_reg = 0.f;
    float h_final = 0.f;

    // ---- prologue: stage x_0 into buf0; load x_1 into xv regs ----
    {
        const float* x0b = X + b0 * DIN;
        float4 t0 = *(const float4*)(x0b + xr0 * DIN + xc4 * 4);
        float4 t1 = *(const float4*)(x0b + xr1 * DIN + xc4 * 4);
        short4v r;
        r.x = (short)f2bf(t0.x); r.y = (short)f2bf(t0.y);
        r.z = (short)f2bf(t0.z); r.w = (short)f2bf(t0.w);
        *(short4v*)(&comb_s[xr0 * LDK + xc4 * 4]) = r;
        r.x = (short)f2bf(t1.x); r.y = (short)f2bf(t1.y);
        r.z = (short)f2bf(t1.z); r.w = (short)f2bf(t1.w);
        *(short4v*)(&comb_s[xr1 * LDK + xc4 * 4]) = r;
    }
    float4 xv0 = *(const float4*)(X + (size_t)BATCH * DIN + b0 * DIN + xr0 * DIN + xc4 * 4);
    float4 xv1 = *(const float4*)(X + (size_t)BATCH * DIN + b0 * DIN + xr1 * DIN + xc4 * 4);
    __syncthreads();

    for (int k = 0; k < T_STEPS; ++k) {
        const int p = k & 1;
        unsigned short* cbuf = &comb_s[p * 16 * LDK];
        const unsigned tag = (unsigned)k;
        const unsigned int* fb =
            hxp + (k & 1) * 65536 + (b0 + hrow) * HID + hc * 16;
        const unsigned int* sb = fb + 131072;    // slow plane
        uint4 a, bq, cq, d;
        const int usefast = fastok_s;            // racy read is fine (hint)

        // ======== phase P: poll h_k; stage h_k + x_k into buf[p] ========
        if (usefast) {
            int tries = NPOLL;
            bool ok = false;
            for (;;) {
                poll_load_sc0(fb, a, bq, cq, d);
                if (tags_ok(a, bq, cq, d, tag)) { ok = true; break; }
                if (--tries == 0) break;
            }
            if (!ok) {                       // bounded fallback: ALWAYS succeeds
                fastok_s = 0;
                for (;;) {
                    poll_load_sc1(sb, a, bq, cq, d);
                    if (tags_ok(a, bq, cq, d, tag)) break;
                    __builtin_amdgcn_s_sleep(1);
                }
            }
        } else {
            for (;;) {
                poll_load_sc1(sb, a, bq, cq, d);
                if (tags_ok(a, bq, cq, d, tag)) break;
                __builtin_amdgcn_s_sleep(1);
            }
        }

        {   // h_k -> comb[p][hrow][DIN + hc*16 ..]
            uint4 p0, p1;
            p0.x = pack2bf(a.x, a.y);   p0.y = pack2bf(a.z, a.w);
            p0.z = pack2bf(bq.x, bq.y); p0.w = pack2bf(bq.z, bq.w);
            p1.x = pack2bf(cq.x, cq.y); p1.y = pack2bf(cq.z, cq.w);
            p1.z = pack2bf(d.x, d.y);   p1.w = pack2bf(d.z, d.w);
            *(uint4*)(&cbuf[hrow * LDK + DIN + hc * 16]) = p0;
            *(uint4*)(&cbuf[hrow * LDK + DIN + hc * 16 + 8]) = p1;
        }
        if (k > 0) {   // x_k from regs (loaded during step k-1's MFMA phase)
            short4v r;
            r.x = (short)f2bf(xv0.x); r.y = (short)f2bf(xv0.y);
            r.z = (short)f2bf(xv0.z); r.w = (short)f2bf(xv0.w);
            *(short4v*)(&cbuf[xr0 * LDK + xc4 * 4]) = r;
            r.x = (short)f2bf(xv1.x); r.y = (short)f2bf(xv1.y);
            r.z = (short)f2bf(xv1.z); r.w = (short)f2bf(xv1.w);
            *(short4v*)(&cbuf[xr1 * LDK + xc4 * 4]) = r;
        }
        __syncthreads();   // the ONE barrier: buf[p] complete

        // ======== phase M: x prefetch (post-barrier!) + MFMA, B from regs ====
        if (k + 1 < T_STEPS) {
            const float* xn = X + (size_t)(k + 1) * BATCH * DIN + b0 * DIN;
            xv0 = *(const float4*)(xn + xr0 * DIN + xc4 * 4);
            xv1 = *(const float4*)(xn + xr1 * DIN + xc4 * 4);
        }
        f32x4 acc0 = {0.f, 0.f, 0.f, 0.f}, acc1 = {0.f, 0.f, 0.f, 0.f};
        const unsigned short* ap = &cbuf[l16 * LDK + quad * 8];
#pragma unroll
        for (int kt = 0; kt < 6; ++kt) {
            short8 a0 = *(const short8*)(ap + (2 * kt) * 32);
            short8 a1 = *(const short8*)(ap + (2 * kt + 1) * 32);
            acc0 = __builtin_amdgcn_mfma_f32_16x16x32_bf16(a0, wb[2 * kt], acc0, 0, 0, 0);
            acc1 = __builtin_amdgcn_mfma_f32_16x16x32_bf16(a1, wb[2 * kt + 1], acc1, 0, 0, 0);
        }

        // ======== phase T: 4x4 lane<->reg butterfly (z stays in wave) =======
        float v0 = acc0[0] + acc1[0];
        float v1 = acc0[1] + acc1[1];
        float v2 = acc0[2] + acc1[2];
        float v3 = acc0[3] + acc1[3];
        const bool o1 = (lane & 1), o2 = (lane & 2);
        float t, u;
        t = o1 ? v0 : v1; u = __shfl_xor(t, 1);
        v1 = o1 ? v1 : u; v0 = o1 ? u : v0;
        t = o1 ? v2 : v3; u = __shfl_xor(t, 1);
        v3 = o1 ? v3 : u; v2 = o1 ? u : v2;
        t = o2 ? v0 : v2; u = __shfl_xor(t, 2);
        v2 = o2 ? v2 : u; v0 = o2 ? u : v0;
        t = o2 ? v1 : v3; u = __shfl_xor(t, 2);
        v3 = o2 ? v3 : u; v1 = o2 ? u : v1;
        // now: v0..v3 = z_f, z_i, z_g, z_o for this thread's (b, j)

        // ======== phase G: gates; dual-store h FIRST; hist ========
        float fg = sigmoid_f(v0 + bb.x);
        float ig = sigmoid_f(v1 + bb.y);
        float gg = tanh_f(v2 + bb.z);
        float og = sigmoid_f(v3 + bb.w);
        c_reg = fg * c_reg + ig * gg;
        float hval = og * tanh_f(c_reg);
        unsigned short hb = f2bf(hval);
        unsigned int hword = ((unsigned)hb << 16) | (unsigned)(k + 1);
        unsigned int* fdst = hxp + ((k + 1) & 1) * 65536 + b * HID + j;
        store_plain_u32(fdst, hword);             // fast plane (same-XCD L2)
        store_sc1_u32(fdst + 131072, hword);      // slow plane (proven path)
        hist[(size_t)k * BATCH * HID + b * HID + j] = hb;
        if (k + 1 == T_STEPS) h_final = hval;
    }

    // epilogue: hx (fp32) and cx outputs
    out[T_STEPS * BATCH * 2 + b * HID + j] = h_final;
    out[T_STEPS * BATCH * 2 + BATCH * HID + b * HID + j] = c_reg;
}

// ---- classifier head: one wave per (t,b) row ----
__global__ __launch_bounds__(256) void probs_k(
    const unsigned short* __restrict__ hist, const float* __restrict__ Wc,
    const float* __restrict__ bc, float* __restrict__ out) {
    const int wave = threadIdx.x >> 6, lane = threadIdx.x & 63;
    const size_t row = (size_t)blockIdx.x * 4 + wave;   // row = t*256+b < 131072
    const unsigned short* h = hist + row * HID;
    short4v hv = *(const short4v*)(h + lane * 4);
    const float4 wv = *(const float4*)(Wc + lane * 4);
    float p = bf2f((unsigned short)hv.x) * wv.x + bf2f((unsigned short)hv.y) * wv.y +
              bf2f((unsigned short)hv.z) * wv.z + bf2f((unsigned short)hv.w) * wv.w;
#pragma unroll
    for (int off = 32; off >= 1; off >>= 1) p += __shfl_down(p, off);
    if (lane == 0) {
        float prob = 1.f / (1.f + __expf(-(p + bc[0])));
        out[row * 2]     = prob;
        out[row * 2 + 1] = 1.f - prob;
    }
}

extern "C" void kernel_launch(void* const* d_in, const int* in_sizes, int n_in,
                              void* d_out, int out_size, void* d_ws, size_t ws_size,
                              hipStream_t stream) {
    const float* X  = (const float*)d_in[0];
    const float* Wf = (const float*)d_in[1];
    const float* bfp= (const float*)d_in[2];
    const float* Wi = (const float*)d_in[3];
    const float* bip= (const float*)d_in[4];
    const float* Wg = (const float*)d_in[5];
    const float* bgp= (const float*)d_in[6];
    const float* Wo = (const float*)d_in[7];
    const float* bop= (const float*)d_in[8];
    const float* Wc = (const float*)d_in[9];
    const float* bc = (const float*)d_in[10];
    float* out = (float*)d_out;

    char* ws = (char*)d_ws;
    unsigned short* Wpack = (unsigned short*)(ws);               // 786432 B
    float* bias = (float*)(ws + 786432);                         // 4096 B
    unsigned int* hxp = (unsigned int*)(ws + 790528);            // 1048576 B
    unsigned short* hist = (unsigned short*)(ws + 1839104);      // 67108864 B

    pack_w<<<1536, 256, 0, stream>>>(Wf, Wi, Wg, Wo, Wpack);
    pack_b<<<4, 256, 0, stream>>>(bfp, bip, bgp, bop, bias);
    init_k<<<256, 256, 0, stream>>>(hxp);

    void* kargs[6] = {(void*)&X, (void*)&Wpack, (void*)&bias,
                      (void*)&hxp, (void*)&hist, (void*)&out};
    (void)hipLaunchCooperativeKernel((const void*)lstm_persist, dim3(GRIDN),
                                     dim3(256), kargs, 0, stream);

    probs_k<<<32768, 256, 0, stream>>>(hist, Wc, bc, out);
}

// Round 6
// 1217.734 us; speedup vs baseline: 3.7883x; 2.5386x over previous
//
#include <hip/hip_runtime.h>
#include <hip/hip_bf16.h>
#include <hip/hip_cooperative_groups.h>

namespace cg = cooperative_groups;

// QLSTM: T=512, B=256, D=128, H=256.  z = [x,h] @ W^T + b, W=[4H,384]
// Round 14: r8/r11 core, minus the per-step vmcnt drain.
//  - LAZY SLOW PLANE: healthy path does ONLY the plain (same-XCD L2) h-store.
//    The sc1 mirror (L3 ack ~600-900cy, drained in-order by the next step's
//    stage/poll vmcnt every step in r8) is gone from the critical path.
//    Deadlock-free insurance: on NPOLL fast-poll failure a thread (hrow,hc)
//    self-mirrors its OWN block's row b0+hrow (both parities, 16 words each,
//    local-L2 reads -> sc1 stores), sets fastok_s=0, then spins sc1; from
//    then on the block dual-stores at gates. Chain spread <=1 step => any
//    stuck block's threads all trip and cover all rows/parities => every
//    needed tag reaches the slow plane => liveness. Healthy cost: zero.
//  - x prefetch issued at TOP of phase M (right after barrier 1, the only
//    legal hiding spot per r12's lesson): ~1100cy of MFMA+z+gates to land,
//    so the next step's stage waits only on (younger) store acks, not HBM.
//  - Everything else r8 verbatim: thread->(b,j) map (coalesced exchange
//    stores: r13's scatter regression), W_s/z_s two-barrier structure,
//    fused-asm poll, tags, NPOLL, r11 XCD-verified role claim.

#define T_STEPS 512
#define BATCH   256
#define DIN     128
#define HID     256
#define KDIM    384
#define LDK     392   // padded LDS row stride (shorts)
#define GRIDN   256
#define NPOLL   96    // bounded fast-poll tries before sc1 fallback

typedef __attribute__((ext_vector_type(8))) short short8;
typedef __attribute__((ext_vector_type(4))) short short4v;
typedef __attribute__((ext_vector_type(4))) float f32x4;

// ---- bootstrap state (device globals; re-zeroed by init_k every launch) ----
__device__ unsigned boot_percxd[8];
__device__ unsigned boot_claimed[8];   // 256-bit role bitmask

__device__ __forceinline__ unsigned short f2bf(float f) {
    unsigned u = __float_as_uint(f);
    unsigned r = (u + 0x7FFFu + ((u >> 16) & 1u)) >> 16;
    return (unsigned short)r;
}
__device__ __forceinline__ float bf2f(unsigned short s) {
    return __uint_as_float(((unsigned)s) << 16);
}
__device__ __forceinline__ float sigmoid_f(float x) {
    return 1.f / (1.f + __expf(-x));
}
__device__ __forceinline__ float tanh_f(float x) {
    float e = __expf(2.f * x);
    return 1.f - 2.f / (e + 1.f);
}
// ---- fused poll loads: 4 x dwordx4 + waitcnt in ONE asm block (r4 idiom) ----
__device__ __forceinline__ void poll_load_sc0(const unsigned int* p, uint4& a,
                                              uint4& b, uint4& c, uint4& d) {
    asm volatile(
        "global_load_dwordx4 %0, %4, off sc0\n\t"
        "global_load_dwordx4 %1, %4, off offset:16 sc0\n\t"
        "global_load_dwordx4 %2, %4, off offset:32 sc0\n\t"
        "global_load_dwordx4 %3, %4, off offset:48 sc0\n\t"
        "s_waitcnt vmcnt(0)"
        : "=&v"(a), "=&v"(b), "=&v"(c), "=&v"(d) : "v"(p) : "memory");
}
__device__ __forceinline__ void poll_load_sc1(const unsigned int* p, uint4& a,
                                              uint4& b, uint4& c, uint4& d) {
    asm volatile(
        "global_load_dwordx4 %0, %4, off sc1\n\t"
        "global_load_dwordx4 %1, %4, off offset:16 sc1\n\t"
        "global_load_dwordx4 %2, %4, off offset:32 sc1\n\t"
        "global_load_dwordx4 %3, %4, off offset:48 sc1\n\t"
        "s_waitcnt vmcnt(0)"
        : "=&v"(a), "=&v"(b), "=&v"(c), "=&v"(d) : "v"(p) : "memory");
}
__device__ __forceinline__ void store_plain_u32(unsigned int* p, unsigned int v) {
    asm volatile("global_store_dword %0, %1, off" :: "v"(p), "v"(v) : "memory");
}
__device__ __forceinline__ void store_sc1_u32(unsigned int* p, unsigned int v) {
    asm volatile("global_store_dword %0, %1, off sc1" :: "v"(p), "v"(v) : "memory");
}
__device__ __forceinline__ unsigned pack2bf(unsigned lo, unsigned hi) {
    return (hi & 0xFFFF0000u) | (lo >> 16);
}
__device__ __forceinline__ bool tags_ok(const uint4& a, const uint4& b,
                                        const uint4& c, const uint4& d,
                                        unsigned tag) {
    return ((a.x ^ tag) & 0xFFFFu) == 0 && ((a.y ^ tag) & 0xFFFFu) == 0 &&
           ((a.z ^ tag) & 0xFFFFu) == 0 && ((a.w ^ tag) & 0xFFFFu) == 0 &&
           ((b.x ^ tag) & 0xFFFFu) == 0 && ((b.y ^ tag) & 0xFFFFu) == 0 &&
           ((b.z ^ tag) & 0xFFFFu) == 0 && ((b.w ^ tag) & 0xFFFFu) == 0 &&
           ((c.x ^ tag) & 0xFFFFu) == 0 && ((c.y ^ tag) & 0xFFFFu) == 0 &&
           ((c.z ^ tag) & 0xFFFFu) == 0 && ((c.w ^ tag) & 0xFFFFu) == 0 &&
           ((d.x ^ tag) & 0xFFFFu) == 0 && ((d.y ^ tag) & 0xFFFFu) == 0 &&
           ((d.z ^ tag) & 0xFFFFu) == 0 && ((d.w ^ tag) & 0xFFFFu) == 0;
}

// ---- pack weights: Wpack[n][k] bf16, n = g*256 + j, row-major [1024][384] ----
__global__ __launch_bounds__(256) void pack_w(
    const float* __restrict__ Wf, const float* __restrict__ Wi,
    const float* __restrict__ Wg, const float* __restrict__ Wo,
    unsigned short* __restrict__ Wp) {
    int idx = blockIdx.x * 256 + threadIdx.x;
    int n = idx / KDIM;
    int k = idx - n * KDIM;
    int g = n >> 8, j = n & 255;
    const float* s = (g == 0) ? Wf : (g == 1) ? Wi : (g == 2) ? Wg : Wo;
    Wp[idx] = f2bf(s[j * KDIM + k]);
}

__global__ __launch_bounds__(256) void pack_b(
    const float* __restrict__ bf, const float* __restrict__ bi,
    const float* __restrict__ bg, const float* __restrict__ bo,
    float* __restrict__ bp) {
    int n = blockIdx.x * 256 + threadIdx.x;
    int g = n >> 8, j = n & 255;
    const float* s = (g == 0) ? bf : (g == 1) ? bi : (g == 2) ? bg : bo;
    bp[n] = s[j];
}

// ---- zero exchange planes + bootstrap state (h_0 = 0, tag 0) ----
__global__ __launch_bounds__(256) void init_k(unsigned int* __restrict__ hxp) {
    int tid = blockIdx.x * 256 + threadIdx.x;   // grid 256 -> 65536
    hxp[tid] = 0u;
    hxp[65536 + tid] = 0u;
    hxp[131072 + tid] = 0u;
    hxp[196608 + tid] = 0u;
    if (tid < 8) {
        boot_percxd[tid] = 0u;
        boot_claimed[tid] = 0u;
    }
}

// ---- persistent LSTM: all 512 steps in one launch ----
__global__ __launch_bounds__(256, 1) void lstm_persist(
    const float* __restrict__ X,            // [T,B,D] fp32
    const unsigned short* __restrict__ W,   // [1024][384] bf16
    const float* __restrict__ bias,         // [1024]
    unsigned int* __restrict__ hxp,         // fast[2][B][H] + slow[2][B][H]
    unsigned short* __restrict__ hist,      // [T][B][H] bf16
    float* __restrict__ out) {
    __shared__ __align__(16) unsigned short W_s[64 * LDK];    // 50176 B
    __shared__ __align__(16) unsigned short comb_s[16 * LDK]; // 12544 B
    __shared__ __align__(16) float z_s[4 * 272];              // 4352 B
    __shared__ int fastok_s;
    __shared__ int role_s;

    const int tid = threadIdx.x;

    // ---- XCD-verified role claim (r11, proven-neutral, keeps placement) ----
    if (tid == 0) {
        unsigned xcc = __builtin_amdgcn_s_getreg((31u << 11) | 20u) & 7u;
        unsigned slot = atomicAdd(&boot_percxd[xcc], 1u);
        int role = -1;
        if (slot < 32u) {
            role = (int)(xcc * 32u + slot);
            atomicOr(&boot_claimed[role >> 5], 1u << (role & 31));
        }
        role_s = role;
        fastok_s = 1;
    }
    __syncthreads();
    cg::this_grid().sync();      // all claims visible before spill scan
    if (role_s < 0) {            // overflow block: grab any unclaimed role
        if (tid == 0) {
            for (int r = 0; r < 256; ++r) {
                unsigned bit = 1u << (r & 31);
                if (!(atomicOr(&boot_claimed[r >> 5], bit) & bit)) {
                    role_s = r;
                    break;
                }
            }
        }
        __syncthreads();
    }
    const int role = role_s;
    const int bg = role >> 4, jg = role & 15;   // chain bg: 16 same-XCD blocks
    const int b0 = bg * 16, j0 = jg * 16;
    const int wave = tid >> 6, lane = tid & 63;
    const int l16 = lane & 15, quad = lane >> 4;
    const int bi = tid >> 4, jj = tid & 15;
    const int b = b0 + bi, j = j0 + jj;

    // stage W tile once: local row = g*16+jr <- global row g*256+j0+jr ; 64x384
#pragma unroll
    for (int c = 0; c < 12; ++c) {
        int q = c * 256 + tid;
        int row = q / 48, c8 = q - row * 48;
        int g = row >> 4, jr = row & 15;
        short8 v = *(const short8*)(W + ((g * 256 + j0 + jr) * KDIM + c8 * 8));
        *(short8*)(&W_s[row * LDK + c8 * 8]) = v;
    }
    const float bs0 = bias[0 * HID + j];
    const float bs1 = bias[1 * HID + j];
    const float bs2 = bias[2 * HID + j];
    const float bs3 = bias[3 * HID + j];

    float c_reg = 0.f;
    float h_final = 0.f;

    const unsigned short* arow = &comb_s[l16 * LDK + quad * 8];
    const unsigned short* brow = &W_s[(wave * 16 + l16) * LDK + quad * 8];
    const int hrow = tid >> 4, hc = tid & 15;
    const int xr0 = tid >> 5, xc4 = tid & 31, xr1 = (tid + 256) >> 5;

    // prefetch x_0
    const float* xb = X + b0 * DIN;
    float4 xv0 = *(const float4*)(xb + xr0 * DIN + xc4 * 4);
    float4 xv1 = *(const float4*)(xb + xr1 * DIN + xc4 * 4);

    __syncthreads();

    for (int k = 0; k < T_STEPS; ++k) {
        const unsigned tag = (unsigned)k;
        const unsigned int* fb =
            hxp + (k & 1) * 65536 + (b0 + hrow) * HID + hc * 16;
        const unsigned int* sb = fb + 131072;    // slow plane
        uint4 a, bq, cq, d;
        const int usefast = fastok_s;            // racy read is fine (hint only)

        // ---- stage x_k from prefetched regs ----
        {
            short4v r;
            r.x = (short)f2bf(xv0.x); r.y = (short)f2bf(xv0.y);
            r.z = (short)f2bf(xv0.z); r.w = (short)f2bf(xv0.w);
            *(short4v*)(&comb_s[xr0 * LDK + xc4 * 4]) = r;
            r.x = (short)f2bf(xv1.x); r.y = (short)f2bf(xv1.y);
            r.z = (short)f2bf(xv1.z); r.w = (short)f2bf(xv1.w);
            *(short4v*)(&comb_s[xr1 * LDK + xc4 * 4]) = r;
        }

        // ---- poll h_k: fast (bounded) then slow (guaranteed) ----
        if (usefast) {
            int tries = NPOLL;
            bool ok = false;
            for (;;) {
                poll_load_sc0(fb, a, bq, cq, d);
                if (tags_ok(a, bq, cq, d, tag)) { ok = true; break; }
                if (--tries == 0) break;
            }
            if (!ok) {
                // ---- SAFETY NET (pathological only): self-mirror own block's
                // row b0+hrow, both parities, local L2 -> slow plane; then
                // permanent dual-store mode + sc1 spin. Deadlock-free: chain
                // spread <=1 step; every stuck block's threads trip and cover
                // all 16 rows x 2 parities of its own data.
                const unsigned int* srow = hxp + (b0 + hrow) * HID + j0;
#pragma unroll
                for (int p2 = 0; p2 < 2; ++p2) {
                    const unsigned int* srp = srow + p2 * 65536;
                    unsigned int* drp = (unsigned int*)(srp) + 131072;
#pragma unroll
                    for (int w = 0; w < 16; ++w) {
                        unsigned v = srp[w];        // own-XCD L2 read
                        store_sc1_u32(drp + w, v);
                    }
                }
                fastok_s = 0;
                for (;;) {
                    poll_load_sc1(sb, a, bq, cq, d);
                    if (tags_ok(a, bq, cq, d, tag)) break;
                    __builtin_amdgcn_s_sleep(1);
                }
            }
        } else {
            for (;;) {
                poll_load_sc1(sb, a, bq, cq, d);
                if (tags_ok(a, bq, cq, d, tag)) break;
                __builtin_amdgcn_s_sleep(1);
            }
        }

        // extract 16 bf16 -> comb_s[hrow][DIN + hc*16 ..]
        {
            uint4 p0, p1;
            p0.x = pack2bf(a.x, a.y);   p0.y = pack2bf(a.z, a.w);
            p0.z = pack2bf(bq.x, bq.y); p0.w = pack2bf(bq.z, bq.w);
            p1.x = pack2bf(cq.x, cq.y); p1.y = pack2bf(cq.z, cq.w);
            p1.z = pack2bf(d.x, d.y);   p1.w = pack2bf(d.z, d.w);
            *(uint4*)(&comb_s[hrow * LDK + DIN + hc * 16]) = p0;
            *(uint4*)(&comb_s[hrow * LDK + DIN + hc * 16 + 8]) = p1;
        }
        __syncthreads();   // barrier 1: comb complete

        // ---- phase M: x prefetch for k+1 (post-barrier hiding spot) + MFMA --
        if (k + 1 < T_STEPS) {
            const float* xn = X + (size_t)(k + 1) * BATCH * DIN + b0 * DIN;
            xv0 = *(const float4*)(xn + xr0 * DIN + xc4 * 4);
            xv1 = *(const float4*)(xn + xr1 * DIN + xc4 * 4);
        }
        f32x4 acc0 = {0.f, 0.f, 0.f, 0.f}, acc1 = {0.f, 0.f, 0.f, 0.f};
#pragma unroll
        for (int kt = 0; kt < 6; ++kt) {
            short8 a0 = *(const short8*)(arow + (2 * kt) * 32);
            short8 b0v = *(const short8*)(brow + (2 * kt) * 32);
            short8 a1 = *(const short8*)(arow + (2 * kt + 1) * 32);
            short8 b1v = *(const short8*)(brow + (2 * kt + 1) * 32);
            acc0 = __builtin_amdgcn_mfma_f32_16x16x32_bf16(a0, b0v, acc0, 0, 0, 0);
            acc1 = __builtin_amdgcn_mfma_f32_16x16x32_bf16(a1, b1v, acc1, 0, 0, 0);
        }
#pragma unroll
        for (int r = 0; r < 4; ++r)
            z_s[wave * 272 + (quad * 4 + r) * 17 + l16] = acc0[r] + acc1[r];
        __syncthreads();   // barrier 2: z staged

        // ---- gates; plain h-store FIRST (critical); cond. mirror; hist ----
        float zf = z_s[0 * 272 + bi * 17 + jj] + bs0;
        float zi = z_s[1 * 272 + bi * 17 + jj] + bs1;
        float zg = z_s[2 * 272 + bi * 17 + jj] + bs2;
        float zo = z_s[3 * 272 + bi * 17 + jj] + bs3;
        float fg = sigmoid_f(zf);
        float ig = sigmoid_f(zi);
        float gg = tanh_f(zg);
        float og = sigmoid_f(zo);
        c_reg = fg * c_reg + ig * gg;
        float hval = og * tanh_f(c_reg);
        unsigned short hb = f2bf(hval);
        unsigned int hword = ((unsigned)hb << 16) | (unsigned)(k + 1);
        unsigned int* fdst = hxp + ((k + 1) & 1) * 65536 + b * HID + j;
        store_plain_u32(fdst, hword);             // fast plane (same-XCD L2)
        if (!fastok_s)                            // insurance mode only
            store_sc1_u32(fdst + 131072, hword);
        hist[(size_t)k * BATCH * HID + b * HID + j] = hb;
        if (k + 1 == T_STEPS) h_final = hval;
    }

    // epilogue: hx (fp32) and cx outputs
    out[T_STEPS * BATCH * 2 + b * HID + j] = h_final;
    out[T_STEPS * BATCH * 2 + BATCH * HID + b * HID + j] = c_reg;
}

// ---- classifier head: one wave per (t,b) row ----
__global__ __launch_bounds__(256) void probs_k(
    const unsigned short* __restrict__ hist, const float* __restrict__ Wc,
    const float* __restrict__ bc, float* __restrict__ out) {
    const int wave = threadIdx.x >> 6, lane = threadIdx.x & 63;
    const size_t row = (size_t)blockIdx.x * 4 + wave;   // row = t*256+b < 131072
    const unsigned short* h = hist + row * HID;
    short4v hv = *(const short4v*)(h + lane * 4);
    const float4 wv = *(const float4*)(Wc + lane * 4);
    float p = bf2f((unsigned short)hv.x) * wv.x + bf2f((unsigned short)hv.y) * wv.y +
              bf2f((unsigned short)hv.z) * wv.z + bf2f((unsigned short)hv.w) * wv.w;
#pragma unroll
    for (int off = 32; off >= 1; off >>= 1) p += __shfl_down(p, off);
    if (lane == 0) {
        float prob = 1.f / (1.f + __expf(-(p + bc[0])));
        out[row * 2]     = prob;
        out[row * 2 + 1] = 1.f - prob;
    }
}

extern "C" void kernel_launch(void* const* d_in, const int* in_sizes, int n_in,
                              void* d_out, int out_size, void* d_ws, size_t ws_size,
                              hipStream_t stream) {
    const float* X  = (const float*)d_in[0];
    const float* Wf = (const float*)d_in[1];
    const float* bfp= (const float*)d_in[2];
    const float* Wi = (const float*)d_in[3];
    const float* bip= (const float*)d_in[4];
    const float* Wg = (const float*)d_in[5];
    const float* bgp= (const float*)d_in[6];
    const float* Wo = (const float*)d_in[7];
    const float* bop= (const float*)d_in[8];
    const float* Wc = (const float*)d_in[9];
    const float* bc = (const float*)d_in[10];
    float* out = (float*)d_out;

    char* ws = (char*)d_ws;
    unsigned short* Wpack = (unsigned short*)(ws);               // 786432 B
    float* bias = (float*)(ws + 786432);                         // 4096 B
    unsigned int* hxp = (unsigned int*)(ws + 790528);            // 1048576 B
    unsigned short* hist = (unsigned short*)(ws + 1839104);      // 67108864 B

    pack_w<<<1536, 256, 0, stream>>>(Wf, Wi, Wg, Wo, Wpack);
    pack_b<<<4, 256, 0, stream>>>(bfp, bip, bgp, bop, bias);
    init_k<<<256, 256, 0, stream>>>(hxp);

    void* kargs[6] = {(void*)&X, (void*)&Wpack, (void*)&bias,
                      (void*)&hxp, (void*)&hist, (void*)&out};
    (void)hipLaunchCooperativeKernel((const void*)lstm_persist, dim3(GRIDN),
                                     dim3(256), kargs, 0, stream);

    probs_k<<<32768, 256, 0, stream>>>(hist, Wc, bc, out);
}

// Round 7
// 1194.301 us; speedup vs baseline: 3.8626x; 1.0196x over previous
//
#include <hip/hip_runtime.h>
#include <hip/hip_bf16.h>
#include <hip/hip_cooperative_groups.h>

namespace cg = cooperative_groups;

// QLSTM: T=512, B=256, D=128, H=256.  z = [x,h] @ W^T + b, W=[4H,384]
// Round 15: r8/r11 verbatim EXCEPT the poll loop issues a 1-dword TAG PROBE
// per round instead of the full 4x dwordx4 read (4x fewer L2 transactions
// per spin round; 16x less data). Theory: chain period = serial path +
// E[max over 16 blocks of jitter]; the dominant jitter source is L2
// request-queue congestion caused by the polls themselves (2 chains/XCD
// x 16 consumers x 256 transactions/round ~ 27 req/cy vs ~16/cy L2 service
// rate). The consumer's 64B segment is written by 16 consecutive lanes of
// ONE producer wave => one coalesced 64B transaction => a single tag dword
// is a valid arrival proxy; the full fused read + 16-tag verify after the
// probe hit preserves correctness (re-probe on partial, liveness intact).
// Round 0 remains r8's immediate full read: zero added latency for the
// already-arrived case. Dual-plane stores, sc1 fallback, XCD role claim,
// two-barrier structure: unchanged from the 1070us baseline.

#define T_STEPS 512
#define BATCH   256
#define DIN     128
#define HID     256
#define KDIM    384
#define LDK     392   // padded LDS row stride (shorts)
#define GRIDN   256
#define NPOLL   96    // bounded fast-poll tries before sc1 fallback

typedef __attribute__((ext_vector_type(8))) short short8;
typedef __attribute__((ext_vector_type(4))) short short4v;
typedef __attribute__((ext_vector_type(4))) float f32x4;

// ---- bootstrap state (device globals; re-zeroed by init_k every launch) ----
__device__ unsigned boot_percxd[8];
__device__ unsigned boot_claimed[8];   // 256-bit role bitmask

__device__ __forceinline__ unsigned short f2bf(float f) {
    unsigned u = __float_as_uint(f);
    unsigned r = (u + 0x7FFFu + ((u >> 16) & 1u)) >> 16;
    return (unsigned short)r;
}
__device__ __forceinline__ float bf2f(unsigned short s) {
    return __uint_as_float(((unsigned)s) << 16);
}
__device__ __forceinline__ float sigmoid_f(float x) {
    return 1.f / (1.f + __expf(-x));
}
__device__ __forceinline__ float tanh_f(float x) {
    float e = __expf(2.f * x);
    return 1.f - 2.f / (e + 1.f);
}
// ---- fused poll loads: 4 x dwordx4 + waitcnt in ONE asm block (r4 idiom) ----
__device__ __forceinline__ void poll_load_sc0(const unsigned int* p, uint4& a,
                                              uint4& b, uint4& c, uint4& d) {
    asm volatile(
        "global_load_dwordx4 %0, %4, off sc0\n\t"
        "global_load_dwordx4 %1, %4, off offset:16 sc0\n\t"
        "global_load_dwordx4 %2, %4, off offset:32 sc0\n\t"
        "global_load_dwordx4 %3, %4, off offset:48 sc0\n\t"
        "s_waitcnt vmcnt(0)"
        : "=&v"(a), "=&v"(b), "=&v"(c), "=&v"(d) : "v"(p) : "memory");
}
__device__ __forceinline__ void poll_load_sc1(const unsigned int* p, uint4& a,
                                              uint4& b, uint4& c, uint4& d) {
    asm volatile(
        "global_load_dwordx4 %0, %4, off sc1\n\t"
        "global_load_dwordx4 %1, %4, off offset:16 sc1\n\t"
        "global_load_dwordx4 %2, %4, off offset:32 sc1\n\t"
        "global_load_dwordx4 %3, %4, off offset:48 sc1\n\t"
        "s_waitcnt vmcnt(0)"
        : "=&v"(a), "=&v"(b), "=&v"(c), "=&v"(d) : "v"(p) : "memory");
}
// ---- 1-dword tag probe (the round-15 change) ----
__device__ __forceinline__ unsigned probe_sc0(const unsigned int* p) {
    unsigned w;
    asm volatile(
        "global_load_dword %0, %1, off sc0\n\t"
        "s_waitcnt vmcnt(0)"
        : "=&v"(w) : "v"(p) : "memory");
    return w;
}
__device__ __forceinline__ void store_plain_u32(unsigned int* p, unsigned int v) {
    asm volatile("global_store_dword %0, %1, off" :: "v"(p), "v"(v) : "memory");
}
__device__ __forceinline__ void store_sc1_u32(unsigned int* p, unsigned int v) {
    asm volatile("global_store_dword %0, %1, off sc1" :: "v"(p), "v"(v) : "memory");
}
__device__ __forceinline__ unsigned pack2bf(unsigned lo, unsigned hi) {
    return (hi & 0xFFFF0000u) | (lo >> 16);
}
__device__ __forceinline__ bool tags_ok(const uint4& a, const uint4& b,
                                        const uint4& c, const uint4& d,
                                        unsigned tag) {
    return ((a.x ^ tag) & 0xFFFFu) == 0 && ((a.y ^ tag) & 0xFFFFu) == 0 &&
           ((a.z ^ tag) & 0xFFFFu) == 0 && ((a.w ^ tag) & 0xFFFFu) == 0 &&
           ((b.x ^ tag) & 0xFFFFu) == 0 && ((b.y ^ tag) & 0xFFFFu) == 0 &&
           ((b.z ^ tag) & 0xFFFFu) == 0 && ((b.w ^ tag) & 0xFFFFu) == 0 &&
           ((c.x ^ tag) & 0xFFFFu) == 0 && ((c.y ^ tag) & 0xFFFFu) == 0 &&
           ((c.z ^ tag) & 0xFFFFu) == 0 && ((c.w ^ tag) & 0xFFFFu) == 0 &&
           ((d.x ^ tag) & 0xFFFFu) == 0 && ((d.y ^ tag) & 0xFFFFu) == 0 &&
           ((d.z ^ tag) & 0xFFFFu) == 0 && ((d.w ^ tag) & 0xFFFFu) == 0;
}

// ---- pack weights: Wpack[n][k] bf16, n = g*256 + j, row-major [1024][384] ----
__global__ __launch_bounds__(256) void pack_w(
    const float* __restrict__ Wf, const float* __restrict__ Wi,
    const float* __restrict__ Wg, const float* __restrict__ Wo,
    unsigned short* __restrict__ Wp) {
    int idx = blockIdx.x * 256 + threadIdx.x;
    int n = idx / KDIM;
    int k = idx - n * KDIM;
    int g = n >> 8, j = n & 255;
    const float* s = (g == 0) ? Wf : (g == 1) ? Wi : (g == 2) ? Wg : Wo;
    Wp[idx] = f2bf(s[j * KDIM + k]);
}

__global__ __launch_bounds__(256) void pack_b(
    const float* __restrict__ bf, const float* __restrict__ bi,
    const float* __restrict__ bg, const float* __restrict__ bo,
    float* __restrict__ bp) {
    int n = blockIdx.x * 256 + threadIdx.x;
    int g = n >> 8, j = n & 255;
    const float* s = (g == 0) ? bf : (g == 1) ? bi : (g == 2) ? bg : bo;
    bp[n] = s[j];
}

// ---- zero exchange planes + bootstrap state (h_0 = 0, tag 0) ----
__global__ __launch_bounds__(256) void init_k(unsigned int* __restrict__ hxp) {
    int tid = blockIdx.x * 256 + threadIdx.x;   // grid 256 -> 65536
    hxp[tid] = 0u;
    hxp[65536 + tid] = 0u;
    hxp[131072 + tid] = 0u;
    hxp[196608 + tid] = 0u;
    if (tid < 8) {
        boot_percxd[tid] = 0u;
        boot_claimed[tid] = 0u;
    }
}

// ---- persistent LSTM: all 512 steps in one launch ----
__global__ __launch_bounds__(256, 1) void lstm_persist(
    const float* __restrict__ X,            // [T,B,D] fp32
    const unsigned short* __restrict__ W,   // [1024][384] bf16
    const float* __restrict__ bias,         // [1024]
    unsigned int* __restrict__ hxp,         // fast[2][B][H] + slow[2][B][H]
    unsigned short* __restrict__ hist,      // [T][B][H] bf16
    float* __restrict__ out) {
    __shared__ __align__(16) unsigned short W_s[64 * LDK];    // 50176 B
    __shared__ __align__(16) unsigned short comb_s[16 * LDK]; // 12544 B
    __shared__ __align__(16) float z_s[4 * 272];              // 4352 B
    __shared__ int fastok_s;
    __shared__ int role_s;

    const int tid = threadIdx.x;

    // ---- XCD-verified role claim (r11, proven-neutral, keeps placement) ----
    if (tid == 0) {
        unsigned xcc = __builtin_amdgcn_s_getreg((31u << 11) | 20u) & 7u;
        unsigned slot = atomicAdd(&boot_percxd[xcc], 1u);
        int role = -1;
        if (slot < 32u) {
            role = (int)(xcc * 32u + slot);
            atomicOr(&boot_claimed[role >> 5], 1u << (role & 31));
        }
        role_s = role;
        fastok_s = 1;
    }
    __syncthreads();
    cg::this_grid().sync();      // all claims visible before spill scan
    if (role_s < 0) {            // overflow block: grab any unclaimed role
        if (tid == 0) {
            for (int r = 0; r < 256; ++r) {
                unsigned bit = 1u << (r & 31);
                if (!(atomicOr(&boot_claimed[r >> 5], bit) & bit)) {
                    role_s = r;
                    break;
                }
            }
        }
        __syncthreads();
    }
    const int role = role_s;
    const int bg = role >> 4, jg = role & 15;   // chain bg: 16 same-XCD blocks
    const int b0 = bg * 16, j0 = jg * 16;
    const int wave = tid >> 6, lane = tid & 63;
    const int l16 = lane & 15, quad = lane >> 4;
    const int bi = tid >> 4, jj = tid & 15;
    const int b = b0 + bi, j = j0 + jj;

    // stage W tile once: local row = g*16+jr <- global row g*256+j0+jr ; 64x384
#pragma unroll
    for (int c = 0; c < 12; ++c) {
        int q = c * 256 + tid;
        int row = q / 48, c8 = q - row * 48;
        int g = row >> 4, jr = row & 15;
        short8 v = *(const short8*)(W + ((g * 256 + j0 + jr) * KDIM + c8 * 8));
        *(short8*)(&W_s[row * LDK + c8 * 8]) = v;
    }
    const float bs0 = bias[0 * HID + j];
    const float bs1 = bias[1 * HID + j];
    const float bs2 = bias[2 * HID + j];
    const float bs3 = bias[3 * HID + j];

    float c_reg = 0.f;
    float h_final = 0.f;

    const unsigned short* arow = &comb_s[l16 * LDK + quad * 8];
    const unsigned short* brow = &W_s[(wave * 16 + l16) * LDK + quad * 8];
    const int hrow = tid >> 4, hc = tid & 15;
    const int xr0 = tid >> 5, xc4 = tid & 31, xr1 = (tid + 256) >> 5;

    // prefetch x_0
    const float* xb = X + b0 * DIN;
    float4 xv0 = *(const float4*)(xb + xr0 * DIN + xc4 * 4);
    float4 xv1 = *(const float4*)(xb + xr1 * DIN + xc4 * 4);

    __syncthreads();

    for (int k = 0; k < T_STEPS; ++k) {
        const unsigned tag = (unsigned)k;
        const unsigned int* fb =
            hxp + (k & 1) * 65536 + (b0 + hrow) * HID + hc * 16;
        const unsigned int* sb = fb + 131072;    // slow plane
        uint4 a, bq, cq, d;
        const int usefast = fastok_s;            // racy read is fine (hint only)

        // ---- stage x_k from prefetched regs ----
        {
            short4v r;
            r.x = (short)f2bf(xv0.x); r.y = (short)f2bf(xv0.y);
            r.z = (short)f2bf(xv0.z); r.w = (short)f2bf(xv0.w);
            *(short4v*)(&comb_s[xr0 * LDK + xc4 * 4]) = r;
            r.x = (short)f2bf(xv1.x); r.y = (short)f2bf(xv1.y);
            r.z = (short)f2bf(xv1.z); r.w = (short)f2bf(xv1.w);
            *(short4v*)(&comb_s[xr1 * LDK + xc4 * 4]) = r;
        }

        // ---- poll h_k: full read round 0, then 1-dword tag probe rounds ----
        if (usefast) {
            bool ok = false;
            poll_load_sc0(fb, a, bq, cq, d);         // round 0: r8 fast path
            if (tags_ok(a, bq, cq, d, tag)) ok = true;
            if (!ok) {
                int tries = NPOLL;
                for (;;) {
                    unsigned w0 = probe_sc0(fb);     // 1 transaction/lane
                    if (((w0 ^ tag) & 0xFFFFu) == 0) {
                        poll_load_sc0(fb, a, bq, cq, d);
                        if (tags_ok(a, bq, cq, d, tag)) { ok = true; break; }
                    }
                    if (--tries == 0) break;
                }
            }
            if (!ok) {                       // bounded fallback: ALWAYS succeeds
                fastok_s = 0;
                for (;;) {
                    poll_load_sc1(sb, a, bq, cq, d);
                    if (tags_ok(a, bq, cq, d, tag)) break;
                    __builtin_amdgcn_s_sleep(1);
                }
            }
        } else {
            for (;;) {
                poll_load_sc1(sb, a, bq, cq, d);
                if (tags_ok(a, bq, cq, d, tag)) break;
                __builtin_amdgcn_s_sleep(1);
            }
        }

        // extract 16 bf16 -> comb_s[hrow][DIN + hc*16 ..]
        {
            uint4 p0, p1;
            p0.x = pack2bf(a.x, a.y);   p0.y = pack2bf(a.z, a.w);
            p0.z = pack2bf(bq.x, bq.y); p0.w = pack2bf(bq.z, bq.w);
            p1.x = pack2bf(cq.x, cq.y); p1.y = pack2bf(cq.z, cq.w);
            p1.z = pack2bf(d.x, d.y);   p1.w = pack2bf(d.z, d.w);
            *(uint4*)(&comb_s[hrow * LDK + DIN + hc * 16]) = p0;
            *(uint4*)(&comb_s[hrow * LDK + DIN + hc * 16 + 8]) = p1;
        }
        __syncthreads();

        // ---- MFMA: z_gate = comb[16x384] * Wg^T, 2 acc chains ----
        f32x4 acc0 = {0.f, 0.f, 0.f, 0.f}, acc1 = {0.f, 0.f, 0.f, 0.f};
#pragma unroll
        for (int kt = 0; kt < 6; ++kt) {
            short8 a0 = *(const short8*)(arow + (2 * kt) * 32);
            short8 b0v = *(const short8*)(brow + (2 * kt) * 32);
            short8 a1 = *(const short8*)(arow + (2 * kt + 1) * 32);
            short8 b1v = *(const short8*)(brow + (2 * kt + 1) * 32);
            acc0 = __builtin_amdgcn_mfma_f32_16x16x32_bf16(a0, b0v, acc0, 0, 0, 0);
            acc1 = __builtin_amdgcn_mfma_f32_16x16x32_bf16(a1, b1v, acc1, 0, 0, 0);
        }
#pragma unroll
        for (int r = 0; r < 4; ++r)
            z_s[wave * 272 + (quad * 4 + r) * 17 + l16] = acc0[r] + acc1[r];
        __syncthreads();

        // ---- gates; h dual-store FIRST (critical), then hist + x prefetch ----
        float zf = z_s[0 * 272 + bi * 17 + jj] + bs0;
        float zi = z_s[1 * 272 + bi * 17 + jj] + bs1;
        float zg = z_s[2 * 272 + bi * 17 + jj] + bs2;
        float zo = z_s[3 * 272 + bi * 17 + jj] + bs3;
        float fg = sigmoid_f(zf);
        float ig = sigmoid_f(zi);
        float gg = tanh_f(zg);
        float og = sigmoid_f(zo);
        c_reg = fg * c_reg + ig * gg;
        float hval = og * tanh_f(c_reg);
        unsigned short hb = f2bf(hval);
        unsigned int hword = ((unsigned)hb << 16) | (unsigned)(k + 1);
        unsigned int* fdst = hxp + ((k + 1) & 1) * 65536 + b * HID + j;
        store_plain_u32(fdst, hword);             // fast plane (same-XCD L2)
        store_sc1_u32(fdst + 131072, hword);      // slow plane (proven path)
        hist[(size_t)k * BATCH * HID + b * HID + j] = hb;
        if (k + 1 < T_STEPS) {
            const float* xn = X + (size_t)(k + 1) * BATCH * DIN + b0 * DIN;
            xv0 = *(const float4*)(xn + xr0 * DIN + xc4 * 4);
            xv1 = *(const float4*)(xn + xr1 * DIN + xc4 * 4);
        } else {
            h_final = hval;
        }
    }

    // epilogue: hx (fp32) and cx outputs
    out[T_STEPS * BATCH * 2 + b * HID + j] = h_final;
    out[T_STEPS * BATCH * 2 + BATCH * HID + b * HID + j] = c_reg;
}

// ---- classifier head: one wave per (t,b) row ----
__global__ __launch_bounds__(256) void probs_k(
    const unsigned short* __restrict__ hist, const float* __restrict__ Wc,
    const float* __restrict__ bc, float* __restrict__ out) {
    const int wave = threadIdx.x >> 6, lane = threadIdx.x & 63;
    const size_t row = (size_t)blockIdx.x * 4 + wave;   // row = t*256+b < 131072
    const unsigned short* h = hist + row * HID;
    short4v hv = *(const short4v*)(h + lane * 4);
    const float4 wv = *(const float4*)(Wc + lane * 4);
    float p = bf2f((unsigned short)hv.x) * wv.x + bf2f((unsigned short)hv.y) * wv.y +
              bf2f((unsigned short)hv.z) * wv.z + bf2f((unsigned short)hv.w) * wv.w;
#pragma unroll
    for (int off = 32; off >= 1; off >>= 1) p += __shfl_down(p, off);
    if (lane == 0) {
        float prob = 1.f / (1.f + __expf(-(p + bc[0])));
        out[row * 2]     = prob;
        out[row * 2 + 1] = 1.f - prob;
    }
}

extern "C" void kernel_launch(void* const* d_in, const int* in_sizes, int n_in,
                              void* d_out, int out_size, void* d_ws, size_t ws_size,
                              hipStream_t stream) {
    const float* X  = (const float*)d_in[0];
    const float* Wf = (const float*)d_in[1];
    const float* bfp= (const float*)d_in[2];
    const float* Wi = (const float*)d_in[3];
    const float* bip= (const float*)d_in[4];
    const float* Wg = (const float*)d_in[5];
    const float* bgp= (const float*)d_in[6];
    const float* Wo = (const float*)d_in[7];
    const float* bop= (const float*)d_in[8];
    const float* Wc = (const float*)d_in[9];
    const float* bc = (const float*)d_in[10];
    float* out = (float*)d_out;

    char* ws = (char*)d_ws;
    unsigned short* Wpack = (unsigned short*)(ws);               // 786432 B
    float* bias = (float*)(ws + 786432);                         // 4096 B
    unsigned int* hxp = (unsigned int*)(ws + 790528);            // 1048576 B
    unsigned short* hist = (unsigned short*)(ws + 1839104);      // 67108864 B

    pack_w<<<1536, 256, 0, stream>>>(Wf, Wi, Wg, Wo, Wpack);
    pack_b<<<4, 256, 0, stream>>>(bfp, bip, bgp, bop, bias);
    init_k<<<256, 256, 0, stream>>>(hxp);

    void* kargs[6] = {(void*)&X, (void*)&Wpack, (void*)&bias,
                      (void*)&hxp, (void*)&hist, (void*)&out};
    (void)hipLaunchCooperativeKernel((const void*)lstm_persist, dim3(GRIDN),
                                     dim3(256), kargs, 0, stream);

    probs_k<<<32768, 256, 0, stream>>>(hist, Wc, bc, out);
}

// Round 8
// 1109.318 us; speedup vs baseline: 4.1585x; 1.0766x over previous
//
#include <hip/hip_runtime.h>
#include <hip/hip_bf16.h>

// QLSTM: T=512, B=256, D=128, H=256.  z = [x,h] @ W^T + b, W=[4H,384]
// Round 16: r8 (proven 1070us baseline) with ONE change: the MFMA B-operand
// (W) moves from LDS to registers. r8's mapping already has wave w = gate g,
// cols j0+l16, so each thread's B-fragments are a fixed 12 x short8 slice of
// W -- loaded once into 48 VGPRs, bit-identical to its old W_s reads. This
// removes 48 of the 96 ds_read_b128 per CU per step (~575cy at the measured
// ~12cy/instr CU throughput) and about half the LDS bank conflicts (r13
// measured exactly 3.35e7 vs r8's 6.71e7 with W_s removed). r13's regression
// came from its bundled store-geometry remap -- NOT this change; here the
// output/store geometry is r8-verbatim.
// LDS padded back to r8's 67.5KB footprint (volatile touch, not DCE-able) so
// dispatch/occupancy conditions match the baseline exactly.
// Poll protocol, tagged dual-plane stores, staging, barriers: r8 verbatim.

#define T_STEPS 512
#define BATCH   256
#define DIN     128
#define HID     256
#define KDIM    384
#define LDK     392   // padded LDS row stride (shorts)
#define GRIDN   256
#define NPOLL   96    // bounded fast-poll tries before sc1 fallback

typedef __attribute__((ext_vector_type(8))) short short8;
typedef __attribute__((ext_vector_type(4))) short short4v;
typedef __attribute__((ext_vector_type(4))) float f32x4;

__device__ __forceinline__ unsigned short f2bf(float f) {
    unsigned u = __float_as_uint(f);
    unsigned r = (u + 0x7FFFu + ((u >> 16) & 1u)) >> 16;
    return (unsigned short)r;
}
__device__ __forceinline__ float bf2f(unsigned short s) {
    return __uint_as_float(((unsigned)s) << 16);
}
__device__ __forceinline__ float sigmoid_f(float x) {
    return 1.f / (1.f + __expf(-x));
}
__device__ __forceinline__ float tanh_f(float x) {
    float e = __expf(2.f * x);
    return 1.f - 2.f / (e + 1.f);
}
// ---- fused poll loads: 4 x dwordx4 + waitcnt in ONE asm block (r4 idiom) ----
__device__ __forceinline__ void poll_load_sc0(const unsigned int* p, uint4& a,
                                              uint4& b, uint4& c, uint4& d) {
    asm volatile(
        "global_load_dwordx4 %0, %4, off sc0\n\t"
        "global_load_dwordx4 %1, %4, off offset:16 sc0\n\t"
        "global_load_dwordx4 %2, %4, off offset:32 sc0\n\t"
        "global_load_dwordx4 %3, %4, off offset:48 sc0\n\t"
        "s_waitcnt vmcnt(0)"
        : "=&v"(a), "=&v"(b), "=&v"(c), "=&v"(d) : "v"(p) : "memory");
}
__device__ __forceinline__ void poll_load_sc1(const unsigned int* p, uint4& a,
                                              uint4& b, uint4& c, uint4& d) {
    asm volatile(
        "global_load_dwordx4 %0, %4, off sc1\n\t"
        "global_load_dwordx4 %1, %4, off offset:16 sc1\n\t"
        "global_load_dwordx4 %2, %4, off offset:32 sc1\n\t"
        "global_load_dwordx4 %3, %4, off offset:48 sc1\n\t"
        "s_waitcnt vmcnt(0)"
        : "=&v"(a), "=&v"(b), "=&v"(c), "=&v"(d) : "v"(p) : "memory");
}
__device__ __forceinline__ void store_plain_u32(unsigned int* p, unsigned int v) {
    asm volatile("global_store_dword %0, %1, off" :: "v"(p), "v"(v) : "memory");
}
__device__ __forceinline__ void store_sc1_u32(unsigned int* p, unsigned int v) {
    asm volatile("global_store_dword %0, %1, off sc1" :: "v"(p), "v"(v) : "memory");
}
__device__ __forceinline__ unsigned pack2bf(unsigned lo, unsigned hi) {
    return (hi & 0xFFFF0000u) | (lo >> 16);
}
__device__ __forceinline__ bool tags_ok(const uint4& a, const uint4& b,
                                        const uint4& c, const uint4& d,
                                        unsigned tag) {
    return ((a.x ^ tag) & 0xFFFFu) == 0 && ((a.y ^ tag) & 0xFFFFu) == 0 &&
           ((a.z ^ tag) & 0xFFFFu) == 0 && ((a.w ^ tag) & 0xFFFFu) == 0 &&
           ((b.x ^ tag) & 0xFFFFu) == 0 && ((b.y ^ tag) & 0xFFFFu) == 0 &&
           ((b.z ^ tag) & 0xFFFFu) == 0 && ((b.w ^ tag) & 0xFFFFu) == 0 &&
           ((c.x ^ tag) & 0xFFFFu) == 0 && ((c.y ^ tag) & 0xFFFFu) == 0 &&
           ((c.z ^ tag) & 0xFFFFu) == 0 && ((c.w ^ tag) & 0xFFFFu) == 0 &&
           ((d.x ^ tag) & 0xFFFFu) == 0 && ((d.y ^ tag) & 0xFFFFu) == 0 &&
           ((d.z ^ tag) & 0xFFFFu) == 0 && ((d.w ^ tag) & 0xFFFFu) == 0;
}

// ---- pack weights: Wpack[n][k] bf16, n = g*256 + j, row-major [1024][384] ----
__global__ __launch_bounds__(256) void pack_w(
    const float* __restrict__ Wf, const float* __restrict__ Wi,
    const float* __restrict__ Wg, const float* __restrict__ Wo,
    unsigned short* __restrict__ Wp) {
    int idx = blockIdx.x * 256 + threadIdx.x;
    int n = idx / KDIM;
    int k = idx - n * KDIM;
    int g = n >> 8, j = n & 255;
    const float* s = (g == 0) ? Wf : (g == 1) ? Wi : (g == 2) ? Wg : Wo;
    Wp[idx] = f2bf(s[j * KDIM + k]);
}

__global__ __launch_bounds__(256) void pack_b(
    const float* __restrict__ bf, const float* __restrict__ bi,
    const float* __restrict__ bg, const float* __restrict__ bo,
    float* __restrict__ bp) {
    int n = blockIdx.x * 256 + threadIdx.x;
    int g = n >> 8, j = n & 255;
    const float* s = (g == 0) ? bf : (g == 1) ? bi : (g == 2) ? bg : bo;
    bp[n] = s[j];
}

// ---- zero all 4 exchange planes: fast[2] + slow[2] (h_0 = 0, tag 0) ----
__global__ __launch_bounds__(256) void init_k(unsigned int* __restrict__ hxp) {
    int tid = blockIdx.x * 256 + threadIdx.x;   // grid 256 -> 65536
    hxp[tid] = 0u;
    hxp[65536 + tid] = 0u;
    hxp[131072 + tid] = 0u;
    hxp[196608 + tid] = 0u;
}

// ---- persistent LSTM: all 512 steps in one launch ----
__global__ __launch_bounds__(256, 1) void lstm_persist(
    const float* __restrict__ X,            // [T,B,D] fp32
    const unsigned short* __restrict__ W,   // [1024][384] bf16
    const float* __restrict__ bias,         // [1024]
    unsigned int* __restrict__ hxp,         // fast[2][B][H] + slow[2][B][H]
    unsigned short* __restrict__ hist,      // [T][B][H] bf16
    float* __restrict__ out) {
    __shared__ __align__(16) unsigned short comb_s[16 * LDK]; // 12544 B
    __shared__ __align__(16) float z_s[4 * 272];              // 4352 B
    __shared__ __align__(16) char pad_s[50176];  // keep r8's 67.5KB footprint
    __shared__ int fastok_s;

    const int tid = threadIdx.x;
    // chain = same (blockIdx % 16): same-XCD under round-robin (r11-verified)
    const int bg = blockIdx.x & 15, jg = blockIdx.x >> 4;
    const int b0 = bg * 16, j0 = jg * 16;
    const int wave = tid >> 6, lane = tid & 63;
    const int l16 = lane & 15, quad = lane >> 4;
    const int bi = tid >> 4, jj = tid & 15;
    const int b = b0 + bi, j = j0 + jj;

    // ---- W slice into REGISTERS (the round-16 change) ----
    // wave w computes gate g=w for cols j0+l16; identical data to r8's W_s
    // reads: W row = wave*256 + j0 + l16, K-slice = kt*32 + quad*8.
    const unsigned short* wrow =
        W + (size_t)(wave * 256 + j0 + l16) * KDIM + quad * 8;
    short8 wb[12];
#pragma unroll
    for (int kt = 0; kt < 12; ++kt) wb[kt] = *(const short8*)(wrow + kt * 32);

    const float bs0 = bias[0 * HID + j];
    const float bs1 = bias[1 * HID + j];
    const float bs2 = bias[2 * HID + j];
    const float bs3 = bias[3 * HID + j];
    if (tid == 0) {
        fastok_s = 1;
        ((volatile char*)pad_s)[0] = 0;   // keep occupancy pad allocated
    }

    float c_reg = 0.f;
    float h_final = 0.f;

    const unsigned short* arow = &comb_s[l16 * LDK + quad * 8];
    const int hrow = tid >> 4, hc = tid & 15;
    const int xr0 = tid >> 5, xc4 = tid & 31, xr1 = (tid + 256) >> 5;

    // prefetch x_0
    const float* xb = X + b0 * DIN;
    float4 xv0 = *(const float4*)(xb + xr0 * DIN + xc4 * 4);
    float4 xv1 = *(const float4*)(xb + xr1 * DIN + xc4 * 4);

    __syncthreads();

    for (int k = 0; k < T_STEPS; ++k) {
        const unsigned tag = (unsigned)k;
        const unsigned int* fb =
            hxp + (k & 1) * 65536 + (b0 + hrow) * HID + hc * 16;
        const unsigned int* sb = fb + 131072;    // slow plane
        uint4 a, bq, cq, d;
        const int usefast = fastok_s;            // racy read is fine (hint only)

        // ---- stage x_k from prefetched regs ----
        {
            short4v r;
            r.x = (short)f2bf(xv0.x); r.y = (short)f2bf(xv0.y);
            r.z = (short)f2bf(xv0.z); r.w = (short)f2bf(xv0.w);
            *(short4v*)(&comb_s[xr0 * LDK + xc4 * 4]) = r;
            r.x = (short)f2bf(xv1.x); r.y = (short)f2bf(xv1.y);
            r.z = (short)f2bf(xv1.z); r.w = (short)f2bf(xv1.w);
            *(short4v*)(&comb_s[xr1 * LDK + xc4 * 4]) = r;
        }

        // ---- poll h_k: fast (bounded) then slow (guaranteed) ----
        if (usefast) {
            int tries = NPOLL;
            bool ok = false;
            for (;;) {
                poll_load_sc0(fb, a, bq, cq, d);
                if (tags_ok(a, bq, cq, d, tag)) { ok = true; break; }
                if (--tries == 0) break;
            }
            if (!ok) {                       // bounded fallback: ALWAYS succeeds
                fastok_s = 0;
                for (;;) {
                    poll_load_sc1(sb, a, bq, cq, d);
                    if (tags_ok(a, bq, cq, d, tag)) break;
                    __builtin_amdgcn_s_sleep(1);
                }
            }
        } else {
            for (;;) {
                poll_load_sc1(sb, a, bq, cq, d);
                if (tags_ok(a, bq, cq, d, tag)) break;
                __builtin_amdgcn_s_sleep(1);
            }
        }

        // extract 16 bf16 -> comb_s[hrow][DIN + hc*16 ..]
        {
            uint4 p0, p1;
            p0.x = pack2bf(a.x, a.y);   p0.y = pack2bf(a.z, a.w);
            p0.z = pack2bf(bq.x, bq.y); p0.w = pack2bf(bq.z, bq.w);
            p1.x = pack2bf(cq.x, cq.y); p1.y = pack2bf(cq.z, cq.w);
            p1.z = pack2bf(d.x, d.y);   p1.w = pack2bf(d.z, d.w);
            *(uint4*)(&comb_s[hrow * LDK + DIN + hc * 16]) = p0;
            *(uint4*)(&comb_s[hrow * LDK + DIN + hc * 16 + 8]) = p1;
        }
        __syncthreads();

        // ---- MFMA: z_gate = comb[16x384] * Wg^T, B from registers ----
        f32x4 acc0 = {0.f, 0.f, 0.f, 0.f}, acc1 = {0.f, 0.f, 0.f, 0.f};
#pragma unroll
        for (int kt = 0; kt < 6; ++kt) {
            short8 a0 = *(const short8*)(arow + (2 * kt) * 32);
            short8 a1 = *(const short8*)(arow + (2 * kt + 1) * 32);
            acc0 = __builtin_amdgcn_mfma_f32_16x16x32_bf16(a0, wb[2 * kt], acc0, 0, 0, 0);
            acc1 = __builtin_amdgcn_mfma_f32_16x16x32_bf16(a1, wb[2 * kt + 1], acc1, 0, 0, 0);
        }
#pragma unroll
        for (int r = 0; r < 4; ++r)
            z_s[wave * 272 + (quad * 4 + r) * 17 + l16] = acc0[r] + acc1[r];
        __syncthreads();

        // ---- gates; h dual-store FIRST (critical), then hist + x prefetch ----
        float zf = z_s[0 * 272 + bi * 17 + jj] + bs0;
        float zi = z_s[1 * 272 + bi * 17 + jj] + bs1;
        float zg = z_s[2 * 272 + bi * 17 + jj] + bs2;
        float zo = z_s[3 * 272 + bi * 17 + jj] + bs3;
        float fg = sigmoid_f(zf);
        float ig = sigmoid_f(zi);
        float gg = tanh_f(zg);
        float og = sigmoid_f(zo);
        c_reg = fg * c_reg + ig * gg;
        float hval = og * tanh_f(c_reg);
        unsigned short hb = f2bf(hval);
        unsigned int hword = ((unsigned)hb << 16) | (unsigned)(k + 1);
        unsigned int* fdst = hxp + ((k + 1) & 1) * 65536 + b * HID + j;
        store_plain_u32(fdst, hword);             // fast plane (producer's L2)
        store_sc1_u32(fdst + 131072, hword);      // slow plane (proven path)
        hist[(size_t)k * BATCH * HID + b * HID + j] = hb;
        if (k + 1 < T_STEPS) {
            const float* xn = X + (size_t)(k + 1) * BATCH * DIN + b0 * DIN;
            xv0 = *(const float4*)(xn + xr0 * DIN + xc4 * 4);
            xv1 = *(const float4*)(xn + xr1 * DIN + xc4 * 4);
        } else {
            h_final = hval;
        }
    }

    // epilogue: hx (fp32) and cx outputs
    out[T_STEPS * BATCH * 2 + b * HID + j] = h_final;
    out[T_STEPS * BATCH * 2 + BATCH * HID + b * HID + j] = c_reg;
}

// ---- classifier head: one wave per (t,b) row ----
__global__ __launch_bounds__(256) void probs_k(
    const unsigned short* __restrict__ hist, const float* __restrict__ Wc,
    const float* __restrict__ bc, float* __restrict__ out) {
    const int wave = threadIdx.x >> 6, lane = threadIdx.x & 63;
    const size_t row = (size_t)blockIdx.x * 4 + wave;   // row = t*256+b < 131072
    const unsigned short* h = hist + row * HID;
    short4v hv = *(const short4v*)(h + lane * 4);
    const float4 wv = *(const float4*)(Wc + lane * 4);
    float p = bf2f((unsigned short)hv.x) * wv.x + bf2f((unsigned short)hv.y) * wv.y +
              bf2f((unsigned short)hv.z) * wv.z + bf2f((unsigned short)hv.w) * wv.w;
#pragma unroll
    for (int off = 32; off >= 1; off >>= 1) p += __shfl_down(p, off);
    if (lane == 0) {
        float prob = 1.f / (1.f + __expf(-(p + bc[0])));
        out[row * 2]     = prob;
        out[row * 2 + 1] = 1.f - prob;
    }
}

extern "C" void kernel_launch(void* const* d_in, const int* in_sizes, int n_in,
                              void* d_out, int out_size, void* d_ws, size_t ws_size,
                              hipStream_t stream) {
    const float* X  = (const float*)d_in[0];
    const float* Wf = (const float*)d_in[1];
    const float* bfp= (const float*)d_in[2];
    const float* Wi = (const float*)d_in[3];
    const float* bip= (const float*)d_in[4];
    const float* Wg = (const float*)d_in[5];
    const float* bgp= (const float*)d_in[6];
    const float* Wo = (const float*)d_in[7];
    const float* bop= (const float*)d_in[8];
    const float* Wc = (const float*)d_in[9];
    const float* bc = (const float*)d_in[10];
    float* out = (float*)d_out;

    char* ws = (char*)d_ws;
    unsigned short* Wpack = (unsigned short*)(ws);               // 786432 B
    float* bias = (float*)(ws + 786432);                         // 4096 B
    unsigned int* hxp = (unsigned int*)(ws + 790528);            // 1048576 B
    unsigned short* hist = (unsigned short*)(ws + 1839104);      // 67108864 B

    pack_w<<<1536, 256, 0, stream>>>(Wf, Wi, Wg, Wo, Wpack);
    pack_b<<<4, 256, 0, stream>>>(bfp, bip, bgp, bop, bias);
    init_k<<<256, 256, 0, stream>>>(hxp);

    void* kargs[6] = {(void*)&X, (void*)&Wpack, (void*)&bias,
                      (void*)&hxp, (void*)&hist, (void*)&out};
    (void)hipLaunchCooperativeKernel((const void*)lstm_persist, dim3(GRIDN),
                                     dim3(256), kargs, 0, stream);

    probs_k<<<32768, 256, 0, stream>>>(hist, Wc, bc, out);
}

// Round 9
// 1102.199 us; speedup vs baseline: 4.1854x; 1.0065x over previous
//
#include <hip/hip_runtime.h>
#include <hip/hip_bf16.h>

// QLSTM: T=512, B=256, D=128, H=256.  z = [x,h] @ W^T + b, W=[4H,384]
// Round 17: r16 (proven 984us: W in registers) + two chain cuts:
//  1) K-SPLIT: x-part MFMA (kt 0-3, depends only on x_k) moved AFTER the
//     h-store, accumulated into acc_x and seeded next step. The h-dependent
//     chain (poll -> MFMA -> gates -> store) drops 4 of 12 kt (~16 fewer
//     ds_read_b128/CU in-chain); the post-store x-MFMA is absorbed by the
//     spin window (VALUBusy shows ~4 poll rounds of waiting exist).
//     comb row = [x_even 0..127 | h 128..383 | x_odd 384..511] (LDK 520):
//     h addressing identical to r16; x parity-double-buffered.
//     Races: x[(k+1)&1] written pre-barrier-1 of step k, read post-barrier-2
//     of step k, next overwritten at step k+2 pre-barrier-1 -> fenced.
//  2) sc0 FAST-PLANE STORE (one line): write-through to L2 so consumers'
//     sc0 polls see h sooner (plain stores may linger in CU write path).
// Everything else r16 verbatim: W-in-regs, poll protocol, dual-plane,
// two-barrier structure, chain = blockIdx&15, LDS footprint pad.

#define T_STEPS 512
#define BATCH   256
#define DIN     128
#define HID     256
#define KDIM    384
#define LDK     520   // comb row stride (shorts): x|h|x' layout
#define GRIDN   256
#define NPOLL   96    // bounded fast-poll tries before sc1 fallback

typedef __attribute__((ext_vector_type(8))) short short8;
typedef __attribute__((ext_vector_type(4))) short short4v;
typedef __attribute__((ext_vector_type(4))) float f32x4;

__device__ __forceinline__ unsigned short f2bf(float f) {
    unsigned u = __float_as_uint(f);
    unsigned r = (u + 0x7FFFu + ((u >> 16) & 1u)) >> 16;
    return (unsigned short)r;
}
__device__ __forceinline__ float bf2f(unsigned short s) {
    return __uint_as_float(((unsigned)s) << 16);
}
__device__ __forceinline__ float sigmoid_f(float x) {
    return 1.f / (1.f + __expf(-x));
}
__device__ __forceinline__ float tanh_f(float x) {
    float e = __expf(2.f * x);
    return 1.f - 2.f / (e + 1.f);
}
// ---- fused poll loads: 4 x dwordx4 + waitcnt in ONE asm block (r4 idiom) ----
__device__ __forceinline__ void poll_load_sc0(const unsigned int* p, uint4& a,
                                              uint4& b, uint4& c, uint4& d) {
    asm volatile(
        "global_load_dwordx4 %0, %4, off sc0\n\t"
        "global_load_dwordx4 %1, %4, off offset:16 sc0\n\t"
        "global_load_dwordx4 %2, %4, off offset:32 sc0\n\t"
        "global_load_dwordx4 %3, %4, off offset:48 sc0\n\t"
        "s_waitcnt vmcnt(0)"
        : "=&v"(a), "=&v"(b), "=&v"(c), "=&v"(d) : "v"(p) : "memory");
}
__device__ __forceinline__ void poll_load_sc1(const unsigned int* p, uint4& a,
                                              uint4& b, uint4& c, uint4& d) {
    asm volatile(
        "global_load_dwordx4 %0, %4, off sc1\n\t"
        "global_load_dwordx4 %1, %4, off offset:16 sc1\n\t"
        "global_load_dwordx4 %2, %4, off offset:32 sc1\n\t"
        "global_load_dwordx4 %3, %4, off offset:48 sc1\n\t"
        "s_waitcnt vmcnt(0)"
        : "=&v"(a), "=&v"(b), "=&v"(c), "=&v"(d) : "v"(p) : "memory");
}
__device__ __forceinline__ void store_sc0_u32(unsigned int* p, unsigned int v) {
    asm volatile("global_store_dword %0, %1, off sc0" :: "v"(p), "v"(v) : "memory");
}
__device__ __forceinline__ void store_sc1_u32(unsigned int* p, unsigned int v) {
    asm volatile("global_store_dword %0, %1, off sc1" :: "v"(p), "v"(v) : "memory");
}
__device__ __forceinline__ unsigned pack2bf(unsigned lo, unsigned hi) {
    return (hi & 0xFFFF0000u) | (lo >> 16);
}
__device__ __forceinline__ bool tags_ok(const uint4& a, const uint4& b,
                                        const uint4& c, const uint4& d,
                                        unsigned tag) {
    return ((a.x ^ tag) & 0xFFFFu) == 0 && ((a.y ^ tag) & 0xFFFFu) == 0 &&
           ((a.z ^ tag) & 0xFFFFu) == 0 && ((a.w ^ tag) & 0xFFFFu) == 0 &&
           ((b.x ^ tag) & 0xFFFFu) == 0 && ((b.y ^ tag) & 0xFFFFu) == 0 &&
           ((b.z ^ tag) & 0xFFFFu) == 0 && ((b.w ^ tag) & 0xFFFFu) == 0 &&
           ((c.x ^ tag) & 0xFFFFu) == 0 && ((c.y ^ tag) & 0xFFFFu) == 0 &&
           ((c.z ^ tag) & 0xFFFFu) == 0 && ((c.w ^ tag) & 0xFFFFu) == 0 &&
           ((d.x ^ tag) & 0xFFFFu) == 0 && ((d.y ^ tag) & 0xFFFFu) == 0 &&
           ((d.z ^ tag) & 0xFFFFu) == 0 && ((d.w ^ tag) & 0xFFFFu) == 0;
}

// ---- pack weights: Wpack[n][k] bf16, n = g*256 + j, row-major [1024][384] ----
__global__ __launch_bounds__(256) void pack_w(
    const float* __restrict__ Wf, const float* __restrict__ Wi,
    const float* __restrict__ Wg, const float* __restrict__ Wo,
    unsigned short* __restrict__ Wp) {
    int idx = blockIdx.x * 256 + threadIdx.x;
    int n = idx / KDIM;
    int k = idx - n * KDIM;
    int g = n >> 8, j = n & 255;
    const float* s = (g == 0) ? Wf : (g == 1) ? Wi : (g == 2) ? Wg : Wo;
    Wp[idx] = f2bf(s[j * KDIM + k]);
}

__global__ __launch_bounds__(256) void pack_b(
    const float* __restrict__ bf, const float* __restrict__ bi,
    const float* __restrict__ bg, const float* __restrict__ bo,
    float* __restrict__ bp) {
    int n = blockIdx.x * 256 + threadIdx.x;
    int g = n >> 8, j = n & 255;
    const float* s = (g == 0) ? bf : (g == 1) ? bi : (g == 2) ? bg : bo;
    bp[n] = s[j];
}

// ---- zero all 4 exchange planes: fast[2] + slow[2] (h_0 = 0, tag 0) ----
__global__ __launch_bounds__(256) void init_k(unsigned int* __restrict__ hxp) {
    int tid = blockIdx.x * 256 + threadIdx.x;   // grid 256 -> 65536
    hxp[tid] = 0u;
    hxp[65536 + tid] = 0u;
    hxp[131072 + tid] = 0u;
    hxp[196608 + tid] = 0u;
}

// ---- persistent LSTM: all 512 steps in one launch ----
__global__ __launch_bounds__(256, 1) void lstm_persist(
    const float* __restrict__ X,            // [T,B,D] fp32
    const unsigned short* __restrict__ W,   // [1024][384] bf16
    const float* __restrict__ bias,         // [1024]
    unsigned int* __restrict__ hxp,         // fast[2][B][H] + slow[2][B][H]
    unsigned short* __restrict__ hist,      // [T][B][H] bf16
    float* __restrict__ out) {
    __shared__ __align__(16) unsigned short comb_s[16 * LDK]; // 16640 B
    __shared__ __align__(16) float z_s[4 * 272];              // 4352 B
    __shared__ __align__(16) char pad_s[46080];  // keep ~67.5KB footprint
    __shared__ int fastok_s;

    const int tid = threadIdx.x;
    // chain = same (blockIdx % 16): same-XCD under round-robin (r11-verified)
    const int bg = blockIdx.x & 15, jg = blockIdx.x >> 4;
    const int b0 = bg * 16, j0 = jg * 16;
    const int wave = tid >> 6, lane = tid & 63;
    const int l16 = lane & 15, quad = lane >> 4;
    const int bi = tid >> 4, jj = tid & 15;
    const int b = b0 + bi, j = j0 + jj;

    // ---- W slice into REGISTERS (r16 proven): wave w = gate, cols j0+l16 ----
    const unsigned short* wrow =
        W + (size_t)(wave * 256 + j0 + l16) * KDIM + quad * 8;
    short8 wb[12];
#pragma unroll
    for (int kt = 0; kt < 12; ++kt) wb[kt] = *(const short8*)(wrow + kt * 32);

    const float bs0 = bias[0 * HID + j];
    const float bs1 = bias[1 * HID + j];
    const float bs2 = bias[2 * HID + j];
    const float bs3 = bias[3 * HID + j];
    if (tid == 0) {
        fastok_s = 1;
        ((volatile char*)pad_s)[0] = 0;   // keep occupancy pad allocated
    }

    float c_reg = 0.f;
    float h_final = 0.f;

    const unsigned short* arow = &comb_s[l16 * LDK + quad * 8];
    const int hrow = tid >> 4, hc = tid & 15;
    const int xr0 = tid >> 5, xc4 = tid & 31, xr1 = (tid + 256) >> 5;

    // ---- prologue: stage x_0 into x_even; prefetch x_1; x-MFMA for x_0 ----
    {
        const float* x0b = X + b0 * DIN;
        float4 t0 = *(const float4*)(x0b + xr0 * DIN + xc4 * 4);
        float4 t1 = *(const float4*)(x0b + xr1 * DIN + xc4 * 4);
        short4v r;
        r.x = (short)f2bf(t0.x); r.y = (short)f2bf(t0.y);
        r.z = (short)f2bf(t0.z); r.w = (short)f2bf(t0.w);
        *(short4v*)(&comb_s[xr0 * LDK + xc4 * 4]) = r;
        r.x = (short)f2bf(t1.x); r.y = (short)f2bf(t1.y);
        r.z = (short)f2bf(t1.z); r.w = (short)f2bf(t1.w);
        *(short4v*)(&comb_s[xr1 * LDK + xc4 * 4]) = r;
    }
    float4 xv0 = *(const float4*)(X + (size_t)BATCH * DIN + b0 * DIN + xr0 * DIN + xc4 * 4);
    float4 xv1 = *(const float4*)(X + (size_t)BATCH * DIN + b0 * DIN + xr1 * DIN + xc4 * 4);
    __syncthreads();

    f32x4 acc_x0 = {0.f, 0.f, 0.f, 0.f}, acc_x1 = {0.f, 0.f, 0.f, 0.f};
#pragma unroll
    for (int kp = 0; kp < 2; ++kp) {   // kt 0..3 on x_even (cols 0..127)
        short8 a0 = *(const short8*)(arow + (2 * kp) * 32);
        short8 a1 = *(const short8*)(arow + (2 * kp + 1) * 32);
        acc_x0 = __builtin_amdgcn_mfma_f32_16x16x32_bf16(a0, wb[2 * kp], acc_x0, 0, 0, 0);
        acc_x1 = __builtin_amdgcn_mfma_f32_16x16x32_bf16(a1, wb[2 * kp + 1], acc_x1, 0, 0, 0);
    }

    for (int k = 0; k < T_STEPS; ++k) {
        const unsigned tag = (unsigned)k;
        const unsigned int* fb =
            hxp + (k & 1) * 65536 + (b0 + hrow) * HID + hc * 16;
        const unsigned int* sb = fb + 131072;    // slow plane
        uint4 a, bq, cq, d;
        const int usefast = fastok_s;            // racy read is fine (hint only)

        // ---- poll h_k: fast (bounded) then slow (guaranteed) ----
        if (usefast) {
            int tries = NPOLL;
            bool ok = false;
            for (;;) {
                poll_load_sc0(fb, a, bq, cq, d);
                if (tags_ok(a, bq, cq, d, tag)) { ok = true; break; }
                if (--tries == 0) break;
            }
            if (!ok) {                       // bounded fallback: ALWAYS succeeds
                fastok_s = 0;
                for (;;) {
                    poll_load_sc1(sb, a, bq, cq, d);
                    if (tags_ok(a, bq, cq, d, tag)) break;
                    __builtin_amdgcn_s_sleep(1);
                }
            }
        } else {
            for (;;) {
                poll_load_sc1(sb, a, bq, cq, d);
                if (tags_ok(a, bq, cq, d, tag)) break;
                __builtin_amdgcn_s_sleep(1);
            }
        }

        // extract 16 bf16 -> comb_s[hrow][128 + hc*16 ..] (h region)
        {
            uint4 p0, p1;
            p0.x = pack2bf(a.x, a.y);   p0.y = pack2bf(a.z, a.w);
            p0.z = pack2bf(bq.x, bq.y); p0.w = pack2bf(bq.z, bq.w);
            p1.x = pack2bf(cq.x, cq.y); p1.y = pack2bf(cq.z, cq.w);
            p1.z = pack2bf(d.x, d.y);   p1.w = pack2bf(d.z, d.w);
            *(uint4*)(&comb_s[hrow * LDK + DIN + hc * 16]) = p0;
            *(uint4*)(&comb_s[hrow * LDK + DIN + hc * 16 + 8]) = p1;
        }
        // stage x_{k+1} into parity region (from regs prefetched last step)
        if (k + 1 < T_STEPS) {
            const int xoff = ((k + 1) & 1) ? 384 : 0;
            short4v r;
            r.x = (short)f2bf(xv0.x); r.y = (short)f2bf(xv0.y);
            r.z = (short)f2bf(xv0.z); r.w = (short)f2bf(xv0.w);
            *(short4v*)(&comb_s[xr0 * LDK + xoff + xc4 * 4]) = r;
            r.x = (short)f2bf(xv1.x); r.y = (short)f2bf(xv1.y);
            r.z = (short)f2bf(xv1.z); r.w = (short)f2bf(xv1.w);
            *(short4v*)(&comb_s[xr1 * LDK + xoff + xc4 * 4]) = r;
        }
        __syncthreads();   // barrier 1: h + x_{k+1} staged

        // ---- h-part MFMA (kt 4..11), seeded with precomputed x-part ----
        f32x4 acc0 = acc_x0, acc1 = acc_x1;
#pragma unroll
        for (int kt = 2; kt < 6; ++kt) {   // cols kt*32: 128..383 = h region
            short8 a0 = *(const short8*)(arow + (2 * kt) * 32);
            short8 a1 = *(const short8*)(arow + (2 * kt + 1) * 32);
            acc0 = __builtin_amdgcn_mfma_f32_16x16x32_bf16(a0, wb[2 * kt], acc0, 0, 0, 0);
            acc1 = __builtin_amdgcn_mfma_f32_16x16x32_bf16(a1, wb[2 * kt + 1], acc1, 0, 0, 0);
        }
#pragma unroll
        for (int r = 0; r < 4; ++r)
            z_s[wave * 272 + (quad * 4 + r) * 17 + l16] = acc0[r] + acc1[r];
        __syncthreads();   // barrier 2: z staged

        // ---- gates; h dual-store FIRST (critical); hist ----
        float zf = z_s[0 * 272 + bi * 17 + jj] + bs0;
        float zi = z_s[1 * 272 + bi * 17 + jj] + bs1;
        float zg = z_s[2 * 272 + bi * 17 + jj] + bs2;
        float zo = z_s[3 * 272 + bi * 17 + jj] + bs3;
        float fg = sigmoid_f(zf);
        float ig = sigmoid_f(zi);
        float gg = tanh_f(zg);
        float og = sigmoid_f(zo);
        c_reg = fg * c_reg + ig * gg;
        float hval = og * tanh_f(c_reg);
        unsigned short hb = f2bf(hval);
        unsigned int hword = ((unsigned)hb << 16) | (unsigned)(k + 1);
        unsigned int* fdst = hxp + ((k + 1) & 1) * 65536 + b * HID + j;
        store_sc0_u32(fdst, hword);               // fast plane: sc0 write-through
        store_sc1_u32(fdst + 131072, hword);      // slow plane (proven path)
        hist[(size_t)k * BATCH * HID + b * HID + j] = hb;

        if (k + 1 < T_STEPS) {
            // x prefetch regs for step k+2
            if (k + 2 < T_STEPS) {
                const float* xn = X + (size_t)(k + 2) * BATCH * DIN + b0 * DIN;
                xv0 = *(const float4*)(xn + xr0 * DIN + xc4 * 4);
                xv1 = *(const float4*)(xn + xr1 * DIN + xc4 * 4);
            }
            // ---- post-store x-part MFMA for step k+1 (off the h-chain) ----
            const int xoff = ((k + 1) & 1) ? 384 : 0;
            f32x4 ax0 = {0.f, 0.f, 0.f, 0.f}, ax1 = {0.f, 0.f, 0.f, 0.f};
#pragma unroll
            for (int kp = 0; kp < 2; ++kp) {
                short8 a0 = *(const short8*)(arow + xoff + (2 * kp) * 32);
                short8 a1 = *(const short8*)(arow + xoff + (2 * kp + 1) * 32);
                ax0 = __builtin_amdgcn_mfma_f32_16x16x32_bf16(a0, wb[2 * kp], ax0, 0, 0, 0);
                ax1 = __builtin_amdgcn_mfma_f32_16x16x32_bf16(a1, wb[2 * kp + 1], ax1, 0, 0, 0);
            }
            acc_x0 = ax0; acc_x1 = ax1;
        } else {
            h_final = hval;
        }
    }

    // epilogue: hx (fp32) and cx outputs
    out[T_STEPS * BATCH * 2 + b * HID + j] = h_final;
    out[T_STEPS * BATCH * 2 + BATCH * HID + b * HID + j] = c_reg;
}

// ---- classifier head: one wave per (t,b) row ----
__global__ __launch_bounds__(256) void probs_k(
    const unsigned short* __restrict__ hist, const float* __restrict__ Wc,
    const float* __restrict__ bc, float* __restrict__ out) {
    const int wave = threadIdx.x >> 6, lane = threadIdx.x & 63;
    const size_t row = (size_t)blockIdx.x * 4 + wave;   // row = t*256+b < 131072
    const unsigned short* h = hist + row * HID;
    short4v hv = *(const short4v*)(h + lane * 4);
    const float4 wv = *(const float4*)(Wc + lane * 4);
    float p = bf2f((unsigned short)hv.x) * wv.x + bf2f((unsigned short)hv.y) * wv.y +
              bf2f((unsigned short)hv.z) * wv.z + bf2f((unsigned short)hv.w) * wv.w;
#pragma unroll
    for (int off = 32; off >= 1; off >>= 1) p += __shfl_down(p, off);
    if (lane == 0) {
        float prob = 1.f / (1.f + __expf(-(p + bc[0])));
        out[row * 2]     = prob;
        out[row * 2 + 1] = 1.f - prob;
    }
}

extern "C" void kernel_launch(void* const* d_in, const int* in_sizes, int n_in,
                              void* d_out, int out_size, void* d_ws, size_t ws_size,
                              hipStream_t stream) {
    const float* X  = (const float*)d_in[0];
    const float* Wf = (const float*)d_in[1];
    const float* bfp= (const float*)d_in[2];
    const float* Wi = (const float*)d_in[3];
    const float* bip= (const float*)d_in[4];
    const float* Wg = (const float*)d_in[5];
    const float* bgp= (const float*)d_in[6];
    const float* Wo = (const float*)d_in[7];
    const float* bop= (const float*)d_in[8];
    const float* Wc = (const float*)d_in[9];
    const float* bc = (const float*)d_in[10];
    float* out = (float*)d_out;

    char* ws = (char*)d_ws;
    unsigned short* Wpack = (unsigned short*)(ws);               // 786432 B
    float* bias = (float*)(ws + 786432);                         // 4096 B
    unsigned int* hxp = (unsigned int*)(ws + 790528);            // 1048576 B
    unsigned short* hist = (unsigned short*)(ws + 1839104);      // 67108864 B

    pack_w<<<1536, 256, 0, stream>>>(Wf, Wi, Wg, Wo, Wpack);
    pack_b<<<4, 256, 0, stream>>>(bfp, bip, bgp, bop, bias);
    init_k<<<256, 256, 0, stream>>>(hxp);

    void* kargs[6] = {(void*)&X, (void*)&Wpack, (void*)&bias,
                      (void*)&hxp, (void*)&hist, (void*)&out};
    (void)hipLaunchCooperativeKernel((const void*)lstm_persist, dim3(GRIDN),
                                     dim3(256), kargs, 0, stream);

    probs_k<<<32768, 256, 0, stream>>>(hist, Wc, bc, out);
}